// Round 9
// baseline (712.017 us; speedup 1.0000x reference)
//
#include <hip/hip_runtime.h>
#include <hip/hip_bf16.h>
#include <stdint.h>

#define B_ 2
#define N_ 4096
#define C_ 512
#define H_ 8
#define D_ 64
#define M_ (B_*N_)     // 8192
#define K3_ (3*C_)     // 1536
#define NCH 4          // KV-split ways

typedef __attribute__((ext_vector_type(8)))  short short8;
typedef __attribute__((ext_vector_type(4)))  float f32x4;
typedef __attribute__((ext_vector_type(16))) float f32x16;

// ---------- helpers ----------
static __device__ __forceinline__ unsigned short f2bf(float f) {
  union { float f; unsigned u; } cv; cv.f = f;
  unsigned r = cv.u + 0x7fffu + ((cv.u >> 16) & 1u);   // RNE
  return (unsigned short)(r >> 16);
}
static __device__ __forceinline__ float bf2f(short x) {
  union { unsigned u; float f; } cv;
  cv.u = ((unsigned)(unsigned short)x) << 16;
  return cv.f;
}
static __device__ __forceinline__ float fexp2(float x) {
#if __has_builtin(__builtin_amdgcn_exp2f)
  return __builtin_amdgcn_exp2f(x);
#else
  return exp2f(x);
#endif
}
static __device__ __forceinline__ unsigned cvt_pk_bf16(float a, float b) {
  unsigned r;
  asm("v_cvt_pk_bf16_f32 %0, %1, %2" : "=v"(r) : "v"(a), "v"(b));
  return r;   // lo = bf16(a), hi = bf16(b)
}
static __device__ __forceinline__ void gload_lds16(const void* g, void* l) {
  __builtin_amdgcn_global_load_lds((const __attribute__((address_space(1))) unsigned*)g,
                                   (__attribute__((address_space(3))) unsigned*)l, 16, 0, 0);
}
static __device__ __forceinline__ f32x16 zero16() {
  f32x16 z;
#pragma unroll
  for (int i = 0; i < 16; i++) z[i] = 0.f;
  return z;
}

// ---------- prep: casts + rope table in one launch ----------
__global__ void prep(const float* __restrict__ x, const float* __restrict__ Wqkv,
                     const float* __restrict__ Wproj,
                     short* __restrict__ xb, short* __restrict__ wqkvb,
                     short* __restrict__ wprjb, float2* __restrict__ tab) {
  int blk = blockIdx.x, t = threadIdx.x;
  if (blk < 4096) {
    int i = blk * 256 + t;
    float4 v = ((const float4*)x)[i];
    short4 o;
    o.x = (short)f2bf(v.x); o.y = (short)f2bf(v.y);
    o.z = (short)f2bf(v.z); o.w = (short)f2bf(v.w);
    ((short4*)xb)[i] = o;
  } else if (blk < 4864) {
    int i = (blk - 4096) * 256 + t;
    float4 v = ((const float4*)Wqkv)[i];
    short4 o;
    o.x = (short)f2bf(v.x); o.y = (short)f2bf(v.y);
    o.z = (short)f2bf(v.z); o.w = (short)f2bf(v.w);
    ((short4*)wqkvb)[i] = o;
  } else if (blk < 5120) {
    int i = (blk - 4864) * 256 + t;
    float4 v = ((const float4*)Wproj)[i];
    short4 o;
    o.x = (short)f2bf(v.x); o.y = (short)f2bf(v.y);
    o.z = (short)f2bf(v.z); o.w = (short)f2bf(v.w);
    ((short4*)wprjb)[i] = o;
  } else {
    int i = (blk - 5120) * 256 + t;   // 4096*32
    int p = i & 31, n = i >> 5;
    float freq = exp2f(-((float)(2 * p) / 64.0f) * 13.287712379549449f);
    float ang = (float)n * freq;
    float s, c;
    sincosf(ang, &s, &c);
    float2 r; r.x = c; r.y = s;
    tab[i] = r;
  }
}

// ---------- rope (frag-ready Qf/Kf) + V frag transpose, one launch ----------
__global__ void rope_vt(const short* __restrict__ qkvb, const float2* __restrict__ tab,
                        short* __restrict__ Qf, short* __restrict__ Kf,
                        short* __restrict__ Vf) {
  __shared__ short tile[32][72];
  int blk = blockIdx.x, t = threadIdx.x;
  if (blk < 4096) {
    int idx = blk * 256 + t;           // 2^20
    int lane  = idx & 63;
    int f     = (idx >> 6) & 3;
    int nblk  = (idx >> 8) & 127;
    int h     = (idx >> 15) & 7;
    int b     = (idx >> 18) & 1;
    int tk    = idx >> 19;             // 0 = q, 1 = k
    int c = lane & 31, hi = lane >> 5;
    int n = nblk * 32 + c;
    int d0 = f * 16 + hi * 8;
    short8 v = *(const short8*)(qkvb + (size_t)(b * N_ + n) * K3_ + tk * C_ + h * D_ + d0);
    const float2* tp = tab + n * 32 + (d0 >> 1);
    float sc = (tk == 0) ? 0.18033688011112042f : 1.0f;  // SCALE * log2(e) on Q
    short8 w;
#pragma unroll
    for (int j = 0; j < 4; j++) {
      float e = bf2f(v[2 * j]), o = bf2f(v[2 * j + 1]);
      float2 cs = tp[j];
      float e2 = (e * cs.x - o * cs.y) * sc;
      float o2 = (e * cs.y + o * cs.x) * sc;
      w[2 * j] = (short)f2bf(e2);
      w[2 * j + 1] = (short)f2bf(o2);
    }
    short* dst = (tk ? Kf : Qf) + (((size_t)((b * H_ + h) * 128 + nblk) * 4 + f) * 512) + lane * 8;
    *(short8*)dst = w;
  } else {
    int blk2 = blk - 4096;             // 2048
    int bh = blk2 >> 7, kblk = blk2 & 127;
    int b = bh >> 3, h = bh & 7;
    int n0 = kblk * 32;
    {
      int row = t >> 3, c8 = t & 7;
      short8 v = *(const short8*)(qkvb + (size_t)(b * N_ + n0 + row) * K3_ + 2 * C_ + h * D_ + c8 * 8);
      *(short8*)&tile[row][c8 * 8] = v;
    }
    __syncthreads();
    {
      int frag = t >> 6, lane = t & 63;
      int hi = lane >> 5, c = lane & 31;
      int g = frag & 1, dblk = frag >> 1;
      short8 w;
#pragma unroll
      for (int j = 0; j < 8; j++) w[j] = tile[g * 16 + hi * 8 + j][dblk * 32 + c];
      *(short8*)(Vf + ((size_t)(bh * 128 + kblk) * 4 + frag) * 512 + lane * 8) = w;
    }
  }
}

// ---------- GEMM (global_load_lds staging) ----------
template<int OUTF32>
__global__ __launch_bounds__(256) void gemm_bt(const short* __restrict__ A, const short* __restrict__ Bw,
                                               const float* __restrict__ bias, void* __restrict__ Cout,
                                               int M, int Nout, int K) {
  __shared__ short As[128 * 32];
  __shared__ short Bs[128 * 32];
  int t = threadIdx.x, lane = t & 63, w = t >> 6, wr = w >> 1, wc = w & 1;
  int tM = blockIdx.x * 128, tN = blockIdx.y * 128;
  int lrow = lane & 15, lhi = lane >> 4;
  f32x4 acc[4][4];
#pragma unroll
  for (int fm = 0; fm < 4; fm++)
#pragma unroll
    for (int fn = 0; fn < 4; fn++)
#pragma unroll
      for (int r = 0; r < 4; r++) acc[fm][fn][r] = 0.f;

  int srow = t >> 2, sq = (t & 3) * 8;
  const short* Ag0 = A  + (size_t)(tM + srow) * K + sq;
  const short* Ag1 = A  + (size_t)(tM + 64 + srow) * K + sq;
  const short* Bg0 = Bw + (size_t)(tN + srow) * K + sq;
  const short* Bg1 = Bw + (size_t)(tN + 64 + srow) * K + sq;
  short* Al0 = As + t * 8;          short* Al1 = As + 2048 + t * 8;
  short* Bl0 = Bs + t * 8;          short* Bl1 = Bs + 2048 + t * 8;

  for (int k0 = 0; k0 < K; k0 += 32) {
    gload_lds16(Ag0 + k0, Al0);
    gload_lds16(Ag1 + k0, Al1);
    gload_lds16(Bg0 + k0, Bl0);
    gload_lds16(Bg1 + k0, Bl1);
    __syncthreads();
    short8 af[4], bfr[4];
#pragma unroll
    for (int f = 0; f < 4; f++) {
      af[f]  = *(const short8*)(As + (wr * 64 + f * 16 + lrow) * 32 + lhi * 8);
      bfr[f] = *(const short8*)(Bs + (wc * 64 + f * 16 + lrow) * 32 + lhi * 8);
    }
#pragma unroll
    for (int fm = 0; fm < 4; fm++)
#pragma unroll
      for (int fn = 0; fn < 4; fn++)
        acc[fm][fn] = __builtin_amdgcn_mfma_f32_16x16x32_bf16(af[fm], bfr[fn], acc[fm][fn], 0, 0, 0);
    __syncthreads();
  }

#pragma unroll
  for (int fn = 0; fn < 4; fn++) {
    int col = tN + wc * 64 + fn * 16 + lrow;
    float bv = bias[col];
#pragma unroll
    for (int fm = 0; fm < 4; fm++) {
      int row0 = tM + wr * 64 + fm * 16 + lhi * 4;
#pragma unroll
      for (int r = 0; r < 4; r++) {
        float v = acc[fm][fn][r] + bv;
        if (OUTF32) ((float*)Cout)[(size_t)(row0 + r) * Nout + col] = v;
        else        ((short*)Cout)[(size_t)(row0 + r) * Nout + col] = (short)f2bf(v);
      }
    }
  }
}

// ---------- attn building blocks ----------
static __device__ __forceinline__ void ld4(short8* dst, const short* p) {
#pragma unroll
  for (int f = 0; f < 4; f++) dst[f] = *(const short8*)(p + f * 512);
}
static __device__ __forceinline__ f32x16 qk4(const short8* k, const short8* q, const f32x16& z0) {
  __builtin_amdgcn_s_setprio(1);
  f32x16 st = __builtin_amdgcn_mfma_f32_32x32x16_bf16(k[0], q[0], z0, 0, 0, 0);
  st = __builtin_amdgcn_mfma_f32_32x32x16_bf16(k[1], q[1], st, 0, 0, 0);
  st = __builtin_amdgcn_mfma_f32_32x32x16_bf16(k[2], q[2], st, 0, 0, 0);
  st = __builtin_amdgcn_mfma_f32_32x32x16_bf16(k[3], q[3], st, 0, 0, 0);
  __builtin_amdgcn_s_setprio(0);
  return st;
}
static __device__ __forceinline__ void soft_pv(const f32x16& st, const short8* v,
                                               f32x16& o0, f32x16& o1, float& lsum) {
  float ls = 0.f;
  unsigned cpk[8];
#pragma unroll
  for (int q2 = 0; q2 < 4; q2++) {
    float e0 = fexp2(st[4 * q2]),     e1 = fexp2(st[4 * q2 + 1]);
    float e2 = fexp2(st[4 * q2 + 2]), e3 = fexp2(st[4 * q2 + 3]);
    ls += (e0 + e1) + (e2 + e3);
    cpk[2 * q2]     = cvt_pk_bf16(e0, e1);
    cpk[2 * q2 + 1] = cvt_pk_bf16(e2, e3);
  }
  lsum += ls;
  unsigned w00 = cpk[0], w02 = cpk[2];
  asm volatile("v_permlane32_swap_b32 %0, %1" : "+v"(w00), "+v"(w02));
  unsigned w01 = cpk[1], w03 = cpk[3];
  asm volatile("v_permlane32_swap_b32 %0, %1" : "+v"(w01), "+v"(w03));
  unsigned w10 = cpk[4], w12 = cpk[6];
  asm volatile("v_permlane32_swap_b32 %0, %1" : "+v"(w10), "+v"(w12));
  unsigned w11 = cpk[5], w13 = cpk[7];
  asm volatile("v_permlane32_swap_b32 %0, %1" : "+v"(w11), "+v"(w13));
  union { unsigned u[4]; short8 s; } u0, u1;
  u0.u[0] = w00; u0.u[1] = w01; u0.u[2] = w02; u0.u[3] = w03;
  u1.u[0] = w10; u1.u[1] = w11; u1.u[2] = w12; u1.u[3] = w13;
  __builtin_amdgcn_s_setprio(1);
  o0 = __builtin_amdgcn_mfma_f32_32x32x16_bf16(u0.s, v[0], o0, 0, 0, 0);
  o0 = __builtin_amdgcn_mfma_f32_32x32x16_bf16(u1.s, v[1], o0, 0, 0, 0);
  o1 = __builtin_amdgcn_mfma_f32_32x32x16_bf16(u0.s, v[2], o1, 0, 0, 0);
  o1 = __builtin_amdgcn_mfma_f32_32x32x16_bf16(u1.s, v[3], o1, 0, 0, 0);
  __builtin_amdgcn_s_setprio(0);
}

// ---------- Flash attention: 4-way KV split, 8 blocks/CU, bf16 partials ----------
__global__ __launch_bounds__(256, 8) void attn(const short* __restrict__ Qf, const short* __restrict__ Kf,
                                               const short* __restrict__ Vf,
                                               short* __restrict__ Op, float* __restrict__ lp) {
  __shared__ short Ks[2][2048];
  __shared__ short Vs[2][2048];
  int bh = blockIdx.x;
  int ch = blockIdx.z;
  int t = threadIdx.x;
  int wv = t >> 6, lane = t & 63;
  int c = lane & 31, hi = lane >> 5;
  int q0 = blockIdx.y * 128 + wv * 32;
  const int nkb = N_ / (NCH * 32);         // 32 kv-blocks of 32 per chunk
  int kb0 = ch * nkb;

  const short* Qb = Qf + ((size_t)(bh * 128 + (q0 >> 5)) * 4) * 512 + lane * 8;
  const short* Kg = Kf + ((size_t)(bh * 128 + kb0) * 4) * 512 + t * 8;
  const short* Vg = Vf + ((size_t)(bh * 128 + kb0) * 4) * 512 + t * 8;

  short8 qf4[4];
  ld4(qf4, Qb);

  const f32x16 z0 = zero16();
  f32x16 o0 = z0, o1 = z0;
  float lsum = 0.f;

  gload_lds16(Kg, &Ks[0][t * 8]);
  gload_lds16(Vg, &Vs[0][t * 8]);
  __syncthreads();

  int buf = 0;
  for (int it = 0; it < nkb; ++it) {
    if (it + 1 < nkb) {
      gload_lds16(Kg + (size_t)(it + 1) * 2048, &Ks[buf ^ 1][t * 8]);
      gload_lds16(Vg + (size_t)(it + 1) * 2048, &Vs[buf ^ 1][t * 8]);
    }
    short8 kf[4], vf[4];
#pragma unroll
    for (int f = 0; f < 4; f++) kf[f] = *(const short8*)&Ks[buf][f * 512 + lane * 8];
#pragma unroll
    for (int f = 0; f < 4; f++) vf[f] = *(const short8*)&Vs[buf][f * 512 + lane * 8];
    f32x16 st = qk4(kf, qf4, z0);
    soft_pv(st, vf, o0, o1, lsum);
    __syncthreads();
    buf ^= 1;
  }

  float lt = lsum + __shfl_xor(lsum, 32);
  if (hi == 0) lp[((size_t)ch * 16 + bh) * N_ + q0 + c] = lt;
  short* obase = Op + ((size_t)ch * 16 + bh) * N_ * D_;
#pragma unroll
  for (int r = 0; r < 16; r++) {
    int ql = (r & 3) + 8 * (r >> 2) + 4 * hi;
    int n = q0 + ql;
    obase[(size_t)n * D_ + c]      = (short)f2bf(o0[r]);
    obase[(size_t)n * D_ + 32 + c] = (short)f2bf(o1[r]);
  }
}

// ---------- combine bf16 partials -> AO bf16 ----------
__global__ void combine(const short* __restrict__ Op, const float* __restrict__ lp,
                        short* __restrict__ AO) {
  int i = blockIdx.x * blockDim.x + threadIdx.x;   // 16*4096*8
  if (i >= 16 * N_ * 8) return;
  int d8 = i & 7, q = (i >> 3) & (N_ - 1), bh = i >> 15;
  const size_t chs = (size_t)16 * N_ * D_;
  size_t base = ((size_t)bh * N_ + q) * D_ + d8 * 8;
  float acc[8];
#pragma unroll
  for (int j = 0; j < 8; j++) acc[j] = 0.f;
  float l = 0.f;
#pragma unroll
  for (int chv = 0; chv < NCH; chv++) {
    short8 v = *(const short8*)(Op + chv * chs + base);
#pragma unroll
    for (int j = 0; j < 8; j++) acc[j] += bf2f(v[j]);
    l += lp[((size_t)chv * 16 + bh) * N_ + q];
  }
  float inv = 1.0f / l;
  int bb = bh >> 3, h = bh & 7;
  short8 o;
#pragma unroll
  for (int j = 0; j < 8; j++) o[j] = (short)f2bf(acc[j] * inv);
  *(short8*)(AO + ((size_t)(bb * N_ + q)) * C_ + h * D_ + d8 * 8) = o;
}

// ---------- launch ----------
extern "C" void kernel_launch(void* const* d_in, const int* in_sizes, int n_in,
                              void* d_out, int out_size, void* d_ws, size_t ws_size,
                              hipStream_t stream) {
  const float* x     = (const float*)d_in[0];
  const float* Wqkv  = (const float*)d_in[1];
  const float* bqkv  = (const float*)d_in[2];
  const float* Wproj = (const float*)d_in[3];
  const float* bproj = (const float*)d_in[4];
  float* out = (float*)d_out;
  char* ws = (char*)d_ws;

  // persistent region
  const size_t off_wprjb = 0;          // 524,288
  const size_t off_tab   = 524288;     // 1,048,576
  const size_t off_q     = 1572864;    // 8,388,608
  const size_t off_k     = 9961472;    // 8,388,608
  const size_t off_vt    = 18350080;   // 8,388,608
  const size_t off_ao    = 26738688;   // 8,388,608 -> ends 35,127,296
  // phase-1 transient (aliased below by partials)
  const size_t off_xb    = 35127296;   // 8,388,608
  const size_t off_wqkvb = 43515904;   // 1,572,864
  const size_t off_qkvb  = 45088768;   // 25,165,824 -> ends 70,254,592
  // attn-phase partials (alias xb/wqkvb/qkvb)
  const size_t off_op    = 35127296;   // 4*16*4096*64*2 = 33,554,432
  const size_t off_l     = 68681728;   // 4*16*4096*4    =  1,048,576 -> ends 69,730,304
  if (ws_size < 70254592) return;

  short* xb    = (short*)(ws + off_xb);
  short* wqkvb = (short*)(ws + off_wqkvb);
  short* wprjb = (short*)(ws + off_wprjb);
  short* qkvb  = (short*)(ws + off_qkvb);
  short* Qfp   = (short*)(ws + off_q);
  short* Kfp   = (short*)(ws + off_k);
  short* Vfp   = (short*)(ws + off_vt);
  short* AOp   = (short*)(ws + off_ao);
  float2* tab  = (float2*)(ws + off_tab);
  short* Opp   = (short*)(ws + off_op);
  float* lpp   = (float*)(ws + off_l);

  prep<<<dim3(5632), dim3(256), 0, stream>>>(x, Wqkv, Wproj, xb, wqkvb, wprjb, tab);

  gemm_bt<0><<<dim3(64, 12), dim3(256), 0, stream>>>(xb, wqkvb, bqkv, qkvb, M_, K3_, C_);

  rope_vt<<<dim3(6144), dim3(256), 0, stream>>>(qkvb, tab, Qfp, Kfp, Vfp);

  attn<<<dim3(16, 32, NCH), dim3(256), 0, stream>>>(Qfp, Kfp, Vfp, Opp, lpp);
  combine<<<dim3(2048), dim3(256), 0, stream>>>(Opp, lpp, AOp);

  gemm_bt<1><<<dim3(64, 4), dim3(256), 0, stream>>>(AOp, wprjb, bproj, (void*)out, M_, C_, C_);
}

// Round 10
// 144.922 us; speedup vs baseline: 4.9131x; 4.9131x over previous
//
#include <hip/hip_runtime.h>
#include <hip/hip_bf16.h>
#include <stdint.h>

#define B_ 2
#define N_ 4096
#define C_ 512
#define H_ 8
#define D_ 64
#define M_ (B_*N_)     // 8192
#define K3_ (3*C_)     // 1536
#define NCH 4          // KV-split ways

typedef __attribute__((ext_vector_type(8)))  short short8;
typedef __attribute__((ext_vector_type(4)))  float f32x4;
typedef __attribute__((ext_vector_type(16))) float f32x16;

// ---------- helpers ----------
static __device__ __forceinline__ unsigned short f2bf(float f) {
  union { float f; unsigned u; } cv; cv.f = f;
  unsigned r = cv.u + 0x7fffu + ((cv.u >> 16) & 1u);   // RNE
  return (unsigned short)(r >> 16);
}
static __device__ __forceinline__ float bf2f(short x) {
  union { unsigned u; float f; } cv;
  cv.u = ((unsigned)(unsigned short)x) << 16;
  return cv.f;
}
static __device__ __forceinline__ float fexp2(float x) {
#if __has_builtin(__builtin_amdgcn_exp2f)
  return __builtin_amdgcn_exp2f(x);
#else
  return exp2f(x);
#endif
}
static __device__ __forceinline__ unsigned cvt_pk_bf16(float a, float b) {
  unsigned r;
  asm("v_cvt_pk_bf16_f32 %0, %1, %2" : "=v"(r) : "v"(a), "v"(b));
  return r;   // lo = bf16(a), hi = bf16(b)
}
static __device__ __forceinline__ void gload_lds16(const void* g, void* l) {
  __builtin_amdgcn_global_load_lds((const __attribute__((address_space(1))) unsigned*)g,
                                   (__attribute__((address_space(3))) unsigned*)l, 16, 0, 0);
}
static __device__ __forceinline__ f32x16 zero16() {
  f32x16 z;
#pragma unroll
  for (int i = 0; i < 16; i++) z[i] = 0.f;
  return z;
}

// ---------- prep: casts + rope table in one launch ----------
__global__ void prep(const float* __restrict__ x, const float* __restrict__ Wqkv,
                     const float* __restrict__ Wproj,
                     short* __restrict__ xb, short* __restrict__ wqkvb,
                     short* __restrict__ wprjb, float2* __restrict__ tab) {
  int blk = blockIdx.x, t = threadIdx.x;
  if (blk < 4096) {
    int i = blk * 256 + t;
    float4 v = ((const float4*)x)[i];
    short4 o;
    o.x = (short)f2bf(v.x); o.y = (short)f2bf(v.y);
    o.z = (short)f2bf(v.z); o.w = (short)f2bf(v.w);
    ((short4*)xb)[i] = o;
  } else if (blk < 4864) {
    int i = (blk - 4096) * 256 + t;
    float4 v = ((const float4*)Wqkv)[i];
    short4 o;
    o.x = (short)f2bf(v.x); o.y = (short)f2bf(v.y);
    o.z = (short)f2bf(v.z); o.w = (short)f2bf(v.w);
    ((short4*)wqkvb)[i] = o;
  } else if (blk < 5120) {
    int i = (blk - 4864) * 256 + t;
    float4 v = ((const float4*)Wproj)[i];
    short4 o;
    o.x = (short)f2bf(v.x); o.y = (short)f2bf(v.y);
    o.z = (short)f2bf(v.z); o.w = (short)f2bf(v.w);
    ((short4*)wprjb)[i] = o;
  } else {
    int i = (blk - 5120) * 256 + t;   // 4096*32
    int p = i & 31, n = i >> 5;
    float freq = exp2f(-((float)(2 * p) / 64.0f) * 13.287712379549449f);
    float ang = (float)n * freq;
    float s, c;
    sincosf(ang, &s, &c);
    float2 r; r.x = c; r.y = s;
    tab[i] = r;
  }
}

// ---------- rope (frag-ready Qf/Kf) + V frag transpose, one launch ----------
__global__ void rope_vt(const short* __restrict__ qkvb, const float2* __restrict__ tab,
                        short* __restrict__ Qf, short* __restrict__ Kf,
                        short* __restrict__ Vf) {
  __shared__ short tile[32][72];
  int blk = blockIdx.x, t = threadIdx.x;
  if (blk < 4096) {
    int idx = blk * 256 + t;           // 2^20
    int lane  = idx & 63;
    int f     = (idx >> 6) & 3;
    int nblk  = (idx >> 8) & 127;
    int h     = (idx >> 15) & 7;
    int b     = (idx >> 18) & 1;
    int tk    = idx >> 19;             // 0 = q, 1 = k
    int c = lane & 31, hi = lane >> 5;
    int n = nblk * 32 + c;
    int d0 = f * 16 + hi * 8;
    short8 v = *(const short8*)(qkvb + (size_t)(b * N_ + n) * K3_ + tk * C_ + h * D_ + d0);
    const float2* tp = tab + n * 32 + (d0 >> 1);
    float sc = (tk == 0) ? 0.18033688011112042f : 1.0f;  // SCALE * log2(e) on Q
    short8 w;
#pragma unroll
    for (int j = 0; j < 4; j++) {
      float e = bf2f(v[2 * j]), o = bf2f(v[2 * j + 1]);
      float2 cs = tp[j];
      float e2 = (e * cs.x - o * cs.y) * sc;
      float o2 = (e * cs.y + o * cs.x) * sc;
      w[2 * j] = (short)f2bf(e2);
      w[2 * j + 1] = (short)f2bf(o2);
    }
    short* dst = (tk ? Kf : Qf) + (((size_t)((b * H_ + h) * 128 + nblk) * 4 + f) * 512) + lane * 8;
    *(short8*)dst = w;
  } else {
    int blk2 = blk - 4096;             // 2048
    int bh = blk2 >> 7, kblk = blk2 & 127;
    int b = bh >> 3, h = bh & 7;
    int n0 = kblk * 32;
    {
      int row = t >> 3, c8 = t & 7;
      short8 v = *(const short8*)(qkvb + (size_t)(b * N_ + n0 + row) * K3_ + 2 * C_ + h * D_ + c8 * 8);
      *(short8*)&tile[row][c8 * 8] = v;
    }
    __syncthreads();
    {
      int frag = t >> 6, lane = t & 63;
      int hi = lane >> 5, c = lane & 31;
      int g = frag & 1, dblk = frag >> 1;
      short8 w;
#pragma unroll
      for (int j = 0; j < 8; j++) w[j] = tile[g * 16 + hi * 8 + j][dblk * 32 + c];
      *(short8*)(Vf + ((size_t)(bh * 128 + kblk) * 4 + frag) * 512 + lane * 8) = w;
    }
  }
}

// ---------- GEMM (global_load_lds staging) ----------
template<int OUTF32>
__global__ __launch_bounds__(256) void gemm_bt(const short* __restrict__ A, const short* __restrict__ Bw,
                                               const float* __restrict__ bias, void* __restrict__ Cout,
                                               int M, int Nout, int K) {
  __shared__ short As[128 * 32];
  __shared__ short Bs[128 * 32];
  int t = threadIdx.x, lane = t & 63, w = t >> 6, wr = w >> 1, wc = w & 1;
  int tM = blockIdx.x * 128, tN = blockIdx.y * 128;
  int lrow = lane & 15, lhi = lane >> 4;
  f32x4 acc[4][4];
#pragma unroll
  for (int fm = 0; fm < 4; fm++)
#pragma unroll
    for (int fn = 0; fn < 4; fn++)
#pragma unroll
      for (int r = 0; r < 4; r++) acc[fm][fn][r] = 0.f;

  int srow = t >> 2, sq = (t & 3) * 8;
  const short* Ag0 = A  + (size_t)(tM + srow) * K + sq;
  const short* Ag1 = A  + (size_t)(tM + 64 + srow) * K + sq;
  const short* Bg0 = Bw + (size_t)(tN + srow) * K + sq;
  const short* Bg1 = Bw + (size_t)(tN + 64 + srow) * K + sq;
  short* Al0 = As + t * 8;          short* Al1 = As + 2048 + t * 8;
  short* Bl0 = Bs + t * 8;          short* Bl1 = Bs + 2048 + t * 8;

  for (int k0 = 0; k0 < K; k0 += 32) {
    gload_lds16(Ag0 + k0, Al0);
    gload_lds16(Ag1 + k0, Al1);
    gload_lds16(Bg0 + k0, Bl0);
    gload_lds16(Bg1 + k0, Bl1);
    __syncthreads();
    short8 af[4], bfr[4];
#pragma unroll
    for (int f = 0; f < 4; f++) {
      af[f]  = *(const short8*)(As + (wr * 64 + f * 16 + lrow) * 32 + lhi * 8);
      bfr[f] = *(const short8*)(Bs + (wc * 64 + f * 16 + lrow) * 32 + lhi * 8);
    }
#pragma unroll
    for (int fm = 0; fm < 4; fm++)
#pragma unroll
      for (int fn = 0; fn < 4; fn++)
        acc[fm][fn] = __builtin_amdgcn_mfma_f32_16x16x32_bf16(af[fm], bfr[fn], acc[fm][fn], 0, 0, 0);
    __syncthreads();
  }

#pragma unroll
  for (int fn = 0; fn < 4; fn++) {
    int col = tN + wc * 64 + fn * 16 + lrow;
    float bv = bias[col];
#pragma unroll
    for (int fm = 0; fm < 4; fm++) {
      int row0 = tM + wr * 64 + fm * 16 + lhi * 4;
#pragma unroll
      for (int r = 0; r < 4; r++) {
        float v = acc[fm][fn][r] + bv;
        if (OUTF32) ((float*)Cout)[(size_t)(row0 + r) * Nout + col] = v;
        else        ((short*)Cout)[(size_t)(row0 + r) * Nout + col] = (short)f2bf(v);
      }
    }
  }
}

// ---------- attn building blocks ----------
static __device__ __forceinline__ void ld4(short8* dst, const short* p) {
#pragma unroll
  for (int f = 0; f < 4; f++) dst[f] = *(const short8*)(p + f * 512);
}
static __device__ __forceinline__ f32x16 qk4(const short8* k, const short8* q, const f32x16& z0) {
  __builtin_amdgcn_s_setprio(1);
  f32x16 st = __builtin_amdgcn_mfma_f32_32x32x16_bf16(k[0], q[0], z0, 0, 0, 0);
  st = __builtin_amdgcn_mfma_f32_32x32x16_bf16(k[1], q[1], st, 0, 0, 0);
  st = __builtin_amdgcn_mfma_f32_32x32x16_bf16(k[2], q[2], st, 0, 0, 0);
  st = __builtin_amdgcn_mfma_f32_32x32x16_bf16(k[3], q[3], st, 0, 0, 0);
  __builtin_amdgcn_s_setprio(0);
  return st;
}
static __device__ __forceinline__ void soft_pv(const f32x16& st, const short8* v,
                                               f32x16& o0, f32x16& o1, float& lsum) {
  float ls = 0.f;
  unsigned cpk[8];
#pragma unroll
  for (int q2 = 0; q2 < 4; q2++) {
    float e0 = fexp2(st[4 * q2]),     e1 = fexp2(st[4 * q2 + 1]);
    float e2 = fexp2(st[4 * q2 + 2]), e3 = fexp2(st[4 * q2 + 3]);
    ls += (e0 + e1) + (e2 + e3);
    cpk[2 * q2]     = cvt_pk_bf16(e0, e1);
    cpk[2 * q2 + 1] = cvt_pk_bf16(e2, e3);
  }
  lsum += ls;
  unsigned w00 = cpk[0], w02 = cpk[2];
  asm volatile("v_permlane32_swap_b32 %0, %1" : "+v"(w00), "+v"(w02));
  unsigned w01 = cpk[1], w03 = cpk[3];
  asm volatile("v_permlane32_swap_b32 %0, %1" : "+v"(w01), "+v"(w03));
  unsigned w10 = cpk[4], w12 = cpk[6];
  asm volatile("v_permlane32_swap_b32 %0, %1" : "+v"(w10), "+v"(w12));
  unsigned w11 = cpk[5], w13 = cpk[7];
  asm volatile("v_permlane32_swap_b32 %0, %1" : "+v"(w11), "+v"(w13));
  union { unsigned u[4]; short8 s; } u0, u1;
  u0.u[0] = w00; u0.u[1] = w01; u0.u[2] = w02; u0.u[3] = w03;
  u1.u[0] = w10; u1.u[1] = w11; u1.u[2] = w12; u1.u[3] = w13;
  __builtin_amdgcn_s_setprio(1);
  o0 = __builtin_amdgcn_mfma_f32_32x32x16_bf16(u0.s, v[0], o0, 0, 0, 0);
  o0 = __builtin_amdgcn_mfma_f32_32x32x16_bf16(u1.s, v[1], o0, 0, 0, 0);
  o1 = __builtin_amdgcn_mfma_f32_32x32x16_bf16(u0.s, v[2], o1, 0, 0, 0);
  o1 = __builtin_amdgcn_mfma_f32_32x32x16_bf16(u1.s, v[3], o1, 0, 0, 0);
  __builtin_amdgcn_s_setprio(0);
}

// ---------- Flash attention: 4-way KV split, 8 blocks/CU, VGPR cap unchanged ----------
__global__ __launch_bounds__(256, 4) void attn(const short* __restrict__ Qf, const short* __restrict__ Kf,
                                               const short* __restrict__ Vf,
                                               short* __restrict__ Op, float* __restrict__ lp) {
  __shared__ short Ks[2][2048];
  __shared__ short Vs[2][2048];
  int bh = blockIdx.x;
  int ch = blockIdx.z;
  int t = threadIdx.x;
  int wv = t >> 6, lane = t & 63;
  int c = lane & 31, hi = lane >> 5;
  int q0 = blockIdx.y * 128 + wv * 32;
  const int nkb = N_ / (NCH * 32);         // 32 kv-blocks of 32 per chunk
  int kb0 = ch * nkb;

  const short* Qb = Qf + ((size_t)(bh * 128 + (q0 >> 5)) * 4) * 512 + lane * 8;
  const short* Kg = Kf + ((size_t)(bh * 128 + kb0) * 4) * 512 + t * 8;
  const short* Vg = Vf + ((size_t)(bh * 128 + kb0) * 4) * 512 + t * 8;

  short8 qf4[4];
  ld4(qf4, Qb);

  const f32x16 z0 = zero16();
  f32x16 o0 = z0, o1 = z0;
  float lsum = 0.f;

  gload_lds16(Kg, &Ks[0][t * 8]);
  gload_lds16(Vg, &Vs[0][t * 8]);
  __syncthreads();

  int buf = 0;
  for (int it = 0; it < nkb; ++it) {
    if (it + 1 < nkb) {
      gload_lds16(Kg + (size_t)(it + 1) * 2048, &Ks[buf ^ 1][t * 8]);
      gload_lds16(Vg + (size_t)(it + 1) * 2048, &Vs[buf ^ 1][t * 8]);
    }
    short8 kf[4], vf[4];
#pragma unroll
    for (int f = 0; f < 4; f++) kf[f] = *(const short8*)&Ks[buf][f * 512 + lane * 8];
#pragma unroll
    for (int f = 0; f < 4; f++) vf[f] = *(const short8*)&Vs[buf][f * 512 + lane * 8];
    f32x16 st = qk4(kf, qf4, z0);
    soft_pv(st, vf, o0, o1, lsum);
    __syncthreads();
    buf ^= 1;
  }

  float lt = lsum + __shfl_xor(lsum, 32);
  if (hi == 0) lp[((size_t)ch * 16 + bh) * N_ + q0 + c] = lt;
  short* obase = Op + ((size_t)ch * 16 + bh) * N_ * D_;
#pragma unroll
  for (int r = 0; r < 16; r++) {
    int ql = (r & 3) + 8 * (r >> 2) + 4 * hi;
    int n = q0 + ql;
    obase[(size_t)n * D_ + c]      = (short)f2bf(o0[r]);
    obase[(size_t)n * D_ + 32 + c] = (short)f2bf(o1[r]);
  }
}

// ---------- combine bf16 partials -> AO bf16 ----------
__global__ void combine(const short* __restrict__ Op, const float* __restrict__ lp,
                        short* __restrict__ AO) {
  int i = blockIdx.x * blockDim.x + threadIdx.x;   // 16*4096*8
  if (i >= 16 * N_ * 8) return;
  int d8 = i & 7, q = (i >> 3) & (N_ - 1), bh = i >> 15;
  const size_t chs = (size_t)16 * N_ * D_;
  size_t base = ((size_t)bh * N_ + q) * D_ + d8 * 8;
  float acc[8];
#pragma unroll
  for (int j = 0; j < 8; j++) acc[j] = 0.f;
  float l = 0.f;
#pragma unroll
  for (int chv = 0; chv < NCH; chv++) {
    short8 v = *(const short8*)(Op + chv * chs + base);
#pragma unroll
    for (int j = 0; j < 8; j++) acc[j] += bf2f(v[j]);
    l += lp[((size_t)chv * 16 + bh) * N_ + q];
  }
  float inv = 1.0f / l;
  int bb = bh >> 3, h = bh & 7;
  short8 o;
#pragma unroll
  for (int j = 0; j < 8; j++) o[j] = (short)f2bf(acc[j] * inv);
  *(short8*)(AO + ((size_t)(bb * N_ + q)) * C_ + h * D_ + d8 * 8) = o;
}

// ---------- launch ----------
extern "C" void kernel_launch(void* const* d_in, const int* in_sizes, int n_in,
                              void* d_out, int out_size, void* d_ws, size_t ws_size,
                              hipStream_t stream) {
  const float* x     = (const float*)d_in[0];
  const float* Wqkv  = (const float*)d_in[1];
  const float* bqkv  = (const float*)d_in[2];
  const float* Wproj = (const float*)d_in[3];
  const float* bproj = (const float*)d_in[4];
  float* out = (float*)d_out;
  char* ws = (char*)d_ws;

  // persistent region
  const size_t off_wprjb = 0;          // 524,288
  const size_t off_tab   = 524288;     // 1,048,576
  const size_t off_q     = 1572864;    // 8,388,608
  const size_t off_k     = 9961472;    // 8,388,608
  const size_t off_vt    = 18350080;   // 8,388,608
  const size_t off_ao    = 26738688;   // 8,388,608 -> ends 35,127,296
  // phase-1 transient (aliased below by partials)
  const size_t off_xb    = 35127296;   // 8,388,608
  const size_t off_wqkvb = 43515904;   // 1,572,864
  const size_t off_qkvb  = 45088768;   // 25,165,824 -> ends 70,254,592
  // attn-phase partials (alias xb/wqkvb/qkvb)
  const size_t off_op    = 35127296;   // 4*16*4096*64*2 = 33,554,432
  const size_t off_l     = 68681728;   // 4*16*4096*4    =  1,048,576 -> ends 69,730,304
  if (ws_size < 70254592) return;

  short* xb    = (short*)(ws + off_xb);
  short* wqkvb = (short*)(ws + off_wqkvb);
  short* wprjb = (short*)(ws + off_wprjb);
  short* qkvb  = (short*)(ws + off_qkvb);
  short* Qfp   = (short*)(ws + off_q);
  short* Kfp   = (short*)(ws + off_k);
  short* Vfp   = (short*)(ws + off_vt);
  short* AOp   = (short*)(ws + off_ao);
  float2* tab  = (float2*)(ws + off_tab);
  short* Opp   = (short*)(ws + off_op);
  float* lpp   = (float*)(ws + off_l);

  prep<<<dim3(5632), dim3(256), 0, stream>>>(x, Wqkv, Wproj, xb, wqkvb, wprjb, tab);

  gemm_bt<0><<<dim3(64, 12), dim3(256), 0, stream>>>(xb, wqkvb, bqkv, qkvb, M_, K3_, C_);

  rope_vt<<<dim3(6144), dim3(256), 0, stream>>>(qkvb, tab, Qfp, Kfp, Vfp);

  attn<<<dim3(16, 32, NCH), dim3(256), 0, stream>>>(Qfp, Kfp, Vfp, Opp, lpp);
  combine<<<dim3(2048), dim3(256), 0, stream>>>(Opp, lpp, AOp);

  gemm_bt<1><<<dim3(64, 4), dim3(256), 0, stream>>>(AOp, wprjb, bproj, (void*)out, M_, C_, C_);
}

// Round 11
// 143.610 us; speedup vs baseline: 4.9580x; 1.0091x over previous
//
#include <hip/hip_runtime.h>
#include <hip/hip_bf16.h>
#include <stdint.h>

#define B_ 2
#define N_ 4096
#define C_ 512
#define H_ 8
#define D_ 64
#define M_ (B_*N_)     // 8192
#define K3_ (3*C_)     // 1536
#define NCH 2          // KV-split ways

typedef __attribute__((ext_vector_type(8)))  short short8;
typedef __attribute__((ext_vector_type(4)))  float f32x4;
typedef __attribute__((ext_vector_type(16))) float f32x16;

// ---------- helpers ----------
static __device__ __forceinline__ unsigned short f2bf(float f) {
  union { float f; unsigned u; } cv; cv.f = f;
  unsigned r = cv.u + 0x7fffu + ((cv.u >> 16) & 1u);   // RNE
  return (unsigned short)(r >> 16);
}
static __device__ __forceinline__ float bf2f(short x) {
  union { unsigned u; float f; } cv;
  cv.u = ((unsigned)(unsigned short)x) << 16;
  return cv.f;
}
static __device__ __forceinline__ float fexp2(float x) {
#if __has_builtin(__builtin_amdgcn_exp2f)
  return __builtin_amdgcn_exp2f(x);
#else
  return exp2f(x);
#endif
}
static __device__ __forceinline__ unsigned cvt_pk_bf16(float a, float b) {
  unsigned r;
  asm("v_cvt_pk_bf16_f32 %0, %1, %2" : "=v"(r) : "v"(a), "v"(b));
  return r;   // lo = bf16(a), hi = bf16(b)
}
static __device__ __forceinline__ void gload_lds16(const void* g, void* l) {
  __builtin_amdgcn_global_load_lds((const __attribute__((address_space(1))) unsigned*)g,
                                   (__attribute__((address_space(3))) unsigned*)l, 16, 0, 0);
}
static __device__ __forceinline__ f32x16 zero16() {
  f32x16 z;
#pragma unroll
  for (int i = 0; i < 16; i++) z[i] = 0.f;
  return z;
}

// ---------- prep: casts + rope table in one launch ----------
__global__ void prep(const float* __restrict__ x, const float* __restrict__ Wqkv,
                     const float* __restrict__ Wproj,
                     short* __restrict__ xb, short* __restrict__ wqkvb,
                     short* __restrict__ wprjb, float2* __restrict__ tab) {
  int blk = blockIdx.x, t = threadIdx.x;
  if (blk < 4096) {
    int i = blk * 256 + t;
    float4 v = ((const float4*)x)[i];
    short4 o;
    o.x = (short)f2bf(v.x); o.y = (short)f2bf(v.y);
    o.z = (short)f2bf(v.z); o.w = (short)f2bf(v.w);
    ((short4*)xb)[i] = o;
  } else if (blk < 4864) {
    int i = (blk - 4096) * 256 + t;
    float4 v = ((const float4*)Wqkv)[i];
    short4 o;
    o.x = (short)f2bf(v.x); o.y = (short)f2bf(v.y);
    o.z = (short)f2bf(v.z); o.w = (short)f2bf(v.w);
    ((short4*)wqkvb)[i] = o;
  } else if (blk < 5120) {
    int i = (blk - 4864) * 256 + t;
    float4 v = ((const float4*)Wproj)[i];
    short4 o;
    o.x = (short)f2bf(v.x); o.y = (short)f2bf(v.y);
    o.z = (short)f2bf(v.z); o.w = (short)f2bf(v.w);
    ((short4*)wprjb)[i] = o;
  } else {
    int i = (blk - 5120) * 256 + t;   // 4096*32
    int p = i & 31, n = i >> 5;
    float freq = exp2f(-((float)(2 * p) / 64.0f) * 13.287712379549449f);
    float ang = (float)n * freq;
    float s, c;
    sincosf(ang, &s, &c);
    float2 r; r.x = c; r.y = s;
    tab[i] = r;
  }
}

// ---------- rope (coalesced LDS-staged) + V frag transpose, one launch ----------
// blocks 0..1023: Q/K rope.  tk = blk>>9, bh = (blk&511)>>5, nb4 = blk&31 (128 rows each)
// blocks 1024..3071: V transpose (bh, kblk)
__global__ void rope_vt(const short* __restrict__ qkvb, const float2* __restrict__ tab,
                        short* __restrict__ Qf, short* __restrict__ Kf,
                        short* __restrict__ Vf) {
  __shared__ short tile[128][72];
  int blk = blockIdx.x, t = threadIdx.x;
  if (blk < 1024) {
    int tk = blk >> 9;
    int bh = (blk & 511) >> 5;
    int nb4 = blk & 31;
    int b = bh >> 3, h = bh & 7;
    int n0 = nb4 * 128;
    // stage 128 rows x 64 shorts, coalesced: 8 threads per row (128B segments)
#pragma unroll
    for (int pass = 0; pass < 4; pass++) {
      int row = pass * 32 + (t >> 3), chunk = t & 7;
      short8 v = *(const short8*)(qkvb + (size_t)(b * N_ + n0 + row) * K3_ + tk * C_ + h * D_ + chunk * 8);
      *(short8*)&tile[row][chunk * 8] = v;
    }
    __syncthreads();
    int lane = t & 63, f = t >> 6;
    int c = lane & 31, hi = lane >> 5;
    int d0 = f * 16 + hi * 8;
    float sc = (tk == 0) ? 0.18033688011112042f : 1.0f;  // SCALE * log2(e) on Q
    short* base = (tk ? Kf : Qf);
#pragma unroll
    for (int i = 0; i < 4; i++) {
      int n_l = i * 32 + c;
      short8 v = *(const short8*)&tile[n_l][d0];
      const float2* tp = tab + (size_t)(n0 + n_l) * 32 + (d0 >> 1);
      short8 w;
#pragma unroll
      for (int j = 0; j < 4; j++) {
        float e = bf2f(v[2 * j]), o = bf2f(v[2 * j + 1]);
        float2 cs = tp[j];
        float e2 = (e * cs.x - o * cs.y) * sc;
        float o2 = (e * cs.y + o * cs.x) * sc;
        w[2 * j] = (short)f2bf(e2);
        w[2 * j + 1] = (short)f2bf(o2);
      }
      short* dst = base + (((size_t)(bh * 128 + nb4 * 4 + i) * 4 + f) * 512) + lane * 8;
      *(short8*)dst = w;
    }
  } else {
    int blk2 = blk - 1024;             // 2048
    int bh = blk2 >> 7, kblk = blk2 & 127;
    int b = bh >> 3, h = bh & 7;
    int n0 = kblk * 32;
    {
      int row = t >> 3, c8 = t & 7;
      short8 v = *(const short8*)(qkvb + (size_t)(b * N_ + n0 + row) * K3_ + 2 * C_ + h * D_ + c8 * 8);
      *(short8*)&tile[row][c8 * 8] = v;
    }
    __syncthreads();
    {
      int frag = t >> 6, lane = t & 63;
      int hi = lane >> 5, c = lane & 31;
      int g = frag & 1, dblk = frag >> 1;
      short8 w;
#pragma unroll
      for (int j = 0; j < 8; j++) w[j] = tile[g * 16 + hi * 8 + j][dblk * 32 + c];
      *(short8*)(Vf + ((size_t)(bh * 128 + kblk) * 4 + frag) * 512 + lane * 8) = w;
    }
  }
}

// ---------- GEMM (global_load_lds staging) ----------
template<int OUTF32>
__global__ __launch_bounds__(256) void gemm_bt(const short* __restrict__ A, const short* __restrict__ Bw,
                                               const float* __restrict__ bias, void* __restrict__ Cout,
                                               int M, int Nout, int K) {
  __shared__ short As[128 * 32];
  __shared__ short Bs[128 * 32];
  int t = threadIdx.x, lane = t & 63, w = t >> 6, wr = w >> 1, wc = w & 1;
  int tM = blockIdx.x * 128, tN = blockIdx.y * 128;
  int lrow = lane & 15, lhi = lane >> 4;
  f32x4 acc[4][4];
#pragma unroll
  for (int fm = 0; fm < 4; fm++)
#pragma unroll
    for (int fn = 0; fn < 4; fn++)
#pragma unroll
      for (int r = 0; r < 4; r++) acc[fm][fn][r] = 0.f;

  int srow = t >> 2, sq = (t & 3) * 8;
  const short* Ag0 = A  + (size_t)(tM + srow) * K + sq;
  const short* Ag1 = A  + (size_t)(tM + 64 + srow) * K + sq;
  const short* Bg0 = Bw + (size_t)(tN + srow) * K + sq;
  const short* Bg1 = Bw + (size_t)(tN + 64 + srow) * K + sq;
  short* Al0 = As + t * 8;          short* Al1 = As + 2048 + t * 8;
  short* Bl0 = Bs + t * 8;          short* Bl1 = Bs + 2048 + t * 8;

  for (int k0 = 0; k0 < K; k0 += 32) {
    gload_lds16(Ag0 + k0, Al0);
    gload_lds16(Ag1 + k0, Al1);
    gload_lds16(Bg0 + k0, Bl0);
    gload_lds16(Bg1 + k0, Bl1);
    __syncthreads();
    short8 af[4], bfr[4];
#pragma unroll
    for (int f = 0; f < 4; f++) {
      af[f]  = *(const short8*)(As + (wr * 64 + f * 16 + lrow) * 32 + lhi * 8);
      bfr[f] = *(const short8*)(Bs + (wc * 64 + f * 16 + lrow) * 32 + lhi * 8);
    }
#pragma unroll
    for (int fm = 0; fm < 4; fm++)
#pragma unroll
      for (int fn = 0; fn < 4; fn++)
        acc[fm][fn] = __builtin_amdgcn_mfma_f32_16x16x32_bf16(af[fm], bfr[fn], acc[fm][fn], 0, 0, 0);
    __syncthreads();
  }

#pragma unroll
  for (int fn = 0; fn < 4; fn++) {
    int col = tN + wc * 64 + fn * 16 + lrow;
    float bv = bias[col];
#pragma unroll
    for (int fm = 0; fm < 4; fm++) {
      int row0 = tM + wr * 64 + fm * 16 + lhi * 4;
#pragma unroll
      for (int r = 0; r < 4; r++) {
        float v = acc[fm][fn][r] + bv;
        if (OUTF32) ((float*)Cout)[(size_t)(row0 + r) * Nout + col] = v;
        else        ((short*)Cout)[(size_t)(row0 + r) * Nout + col] = (short)f2bf(v);
      }
    }
  }
}

// ---------- attn building blocks ----------
static __device__ __forceinline__ void ld4(short8* dst, const short* p) {
#pragma unroll
  for (int f = 0; f < 4; f++) dst[f] = *(const short8*)(p + f * 512);
}
static __device__ __forceinline__ f32x16 qk4(const short8* k, const short8* q, const f32x16& z0) {
  __builtin_amdgcn_s_setprio(1);
  f32x16 st = __builtin_amdgcn_mfma_f32_32x32x16_bf16(k[0], q[0], z0, 0, 0, 0);
  st = __builtin_amdgcn_mfma_f32_32x32x16_bf16(k[1], q[1], st, 0, 0, 0);
  st = __builtin_amdgcn_mfma_f32_32x32x16_bf16(k[2], q[2], st, 0, 0, 0);
  st = __builtin_amdgcn_mfma_f32_32x32x16_bf16(k[3], q[3], st, 0, 0, 0);
  __builtin_amdgcn_s_setprio(0);
  return st;
}
static __device__ __forceinline__ void soft_pv(const f32x16& st, const short8* v,
                                               f32x16& o0, f32x16& o1, float& lsum) {
  float ls = 0.f;
  unsigned cpk[8];
#pragma unroll
  for (int q2 = 0; q2 < 4; q2++) {
    float e0 = fexp2(st[4 * q2]),     e1 = fexp2(st[4 * q2 + 1]);
    float e2 = fexp2(st[4 * q2 + 2]), e3 = fexp2(st[4 * q2 + 3]);
    ls += (e0 + e1) + (e2 + e3);
    cpk[2 * q2]     = cvt_pk_bf16(e0, e1);
    cpk[2 * q2 + 1] = cvt_pk_bf16(e2, e3);
  }
  lsum += ls;
  unsigned w00 = cpk[0], w02 = cpk[2];
  asm volatile("v_permlane32_swap_b32 %0, %1" : "+v"(w00), "+v"(w02));
  unsigned w01 = cpk[1], w03 = cpk[3];
  asm volatile("v_permlane32_swap_b32 %0, %1" : "+v"(w01), "+v"(w03));
  unsigned w10 = cpk[4], w12 = cpk[6];
  asm volatile("v_permlane32_swap_b32 %0, %1" : "+v"(w10), "+v"(w12));
  unsigned w11 = cpk[5], w13 = cpk[7];
  asm volatile("v_permlane32_swap_b32 %0, %1" : "+v"(w11), "+v"(w13));
  union { unsigned u[4]; short8 s; } u0, u1;
  u0.u[0] = w00; u0.u[1] = w01; u0.u[2] = w02; u0.u[3] = w03;
  u1.u[0] = w10; u1.u[1] = w11; u1.u[2] = w12; u1.u[3] = w13;
  __builtin_amdgcn_s_setprio(1);
  o0 = __builtin_amdgcn_mfma_f32_32x32x16_bf16(u0.s, v[0], o0, 0, 0, 0);
  o0 = __builtin_amdgcn_mfma_f32_32x32x16_bf16(u1.s, v[1], o0, 0, 0, 0);
  o1 = __builtin_amdgcn_mfma_f32_32x32x16_bf16(u0.s, v[2], o1, 0, 0, 0);
  o1 = __builtin_amdgcn_mfma_f32_32x32x16_bf16(u1.s, v[3], o1, 0, 0, 0);
  __builtin_amdgcn_s_setprio(0);
}

// ---------- Flash attention: 2-way KV split, LDS-staged K/V, bf16 partials ----------
__global__ __launch_bounds__(256, 4) void attn(const short* __restrict__ Qf, const short* __restrict__ Kf,
                                               const short* __restrict__ Vf,
                                               short* __restrict__ Op, float* __restrict__ lp) {
  __shared__ short Ks[2][2048];
  __shared__ short Vs[2][2048];
  int bh = blockIdx.x;
  int ch = blockIdx.z;
  int t = threadIdx.x;
  int wv = t >> 6, lane = t & 63;
  int c = lane & 31, hi = lane >> 5;
  int q0 = blockIdx.y * 128 + wv * 32;
  const int nkb = N_ / (NCH * 32);
  int kb0 = ch * nkb;

  const short* Qb = Qf + ((size_t)(bh * 128 + (q0 >> 5)) * 4) * 512 + lane * 8;
  const short* Kg = Kf + ((size_t)(bh * 128 + kb0) * 4) * 512 + t * 8;
  const short* Vg = Vf + ((size_t)(bh * 128 + kb0) * 4) * 512 + t * 8;

  short8 qf4[4];
  ld4(qf4, Qb);

  const f32x16 z0 = zero16();
  f32x16 o0 = z0, o1 = z0;
  float lsum = 0.f;

  gload_lds16(Kg, &Ks[0][t * 8]);
  gload_lds16(Vg, &Vs[0][t * 8]);
  __syncthreads();

  int buf = 0;
  for (int it = 0; it < nkb; ++it) {
    if (it + 1 < nkb) {
      gload_lds16(Kg + (size_t)(it + 1) * 2048, &Ks[buf ^ 1][t * 8]);
      gload_lds16(Vg + (size_t)(it + 1) * 2048, &Vs[buf ^ 1][t * 8]);
    }
    short8 kf[4], vf[4];
#pragma unroll
    for (int f = 0; f < 4; f++) kf[f] = *(const short8*)&Ks[buf][f * 512 + lane * 8];
#pragma unroll
    for (int f = 0; f < 4; f++) vf[f] = *(const short8*)&Vs[buf][f * 512 + lane * 8];
    f32x16 st = qk4(kf, qf4, z0);
    soft_pv(st, vf, o0, o1, lsum);
    __syncthreads();
    buf ^= 1;
  }

  float lt = lsum + __shfl_xor(lsum, 32);
  if (hi == 0) lp[((size_t)ch * 16 + bh) * N_ + q0 + c] = lt;
  short* obase = Op + ((size_t)ch * 16 + bh) * N_ * D_;
#pragma unroll
  for (int r = 0; r < 16; r++) {
    int ql = (r & 3) + 8 * (r >> 2) + 4 * hi;
    int n = q0 + ql;
    obase[(size_t)n * D_ + c]      = (short)f2bf(o0[r]);
    obase[(size_t)n * D_ + 32 + c] = (short)f2bf(o1[r]);
  }
}

// ---------- combine bf16 partials -> AO bf16 ----------
__global__ void combine(const short* __restrict__ Op, const float* __restrict__ lp,
                        short* __restrict__ AO) {
  int i = blockIdx.x * blockDim.x + threadIdx.x;   // 16*4096*8
  if (i >= 16 * N_ * 8) return;
  int d8 = i & 7, q = (i >> 3) & (N_ - 1), bh = i >> 15;
  const size_t chs = (size_t)16 * N_ * D_;
  size_t base = ((size_t)bh * N_ + q) * D_ + d8 * 8;
  float acc[8];
#pragma unroll
  for (int j = 0; j < 8; j++) acc[j] = 0.f;
  float l = 0.f;
#pragma unroll
  for (int chv = 0; chv < NCH; chv++) {
    short8 v = *(const short8*)(Op + chv * chs + base);
#pragma unroll
    for (int j = 0; j < 8; j++) acc[j] += bf2f(v[j]);
    l += lp[((size_t)chv * 16 + bh) * N_ + q];
  }
  float inv = 1.0f / l;
  int bb = bh >> 3, h = bh & 7;
  short8 o;
#pragma unroll
  for (int j = 0; j < 8; j++) o[j] = (short)f2bf(acc[j] * inv);
  *(short8*)(AO + ((size_t)(bb * N_ + q)) * C_ + h * D_ + d8 * 8) = o;
}

// ---------- launch ----------
extern "C" void kernel_launch(void* const* d_in, const int* in_sizes, int n_in,
                              void* d_out, int out_size, void* d_ws, size_t ws_size,
                              hipStream_t stream) {
  const float* x     = (const float*)d_in[0];
  const float* Wqkv  = (const float*)d_in[1];
  const float* bqkv  = (const float*)d_in[2];
  const float* Wproj = (const float*)d_in[3];
  const float* bproj = (const float*)d_in[4];
  float* out = (float*)d_out;
  char* ws = (char*)d_ws;

  // persistent region
  const size_t off_wprjb = 0;          // 524,288
  const size_t off_tab   = 524288;     // 1,048,576
  const size_t off_q     = 1572864;    // 8,388,608
  const size_t off_k     = 9961472;    // 8,388,608
  const size_t off_vt    = 18350080;   // 8,388,608
  const size_t off_ao    = 26738688;   // 8,388,608 -> ends 35,127,296
  // phase-1 transient (aliased below by partials)
  const size_t off_xb    = 35127296;   // 8,388,608
  const size_t off_wqkvb = 43515904;   // 1,572,864
  const size_t off_qkvb  = 45088768;   // 25,165,824 -> ends 70,254,592
  // attn-phase partials (alias xb/wqkvb/qkvb)
  const size_t off_op    = 35127296;   // 2*16*4096*64*2 = 16,777,216
  const size_t off_l     = 68681728;   // 2*16*4096*4    =    524,288
  if (ws_size < 70254592) return;

  short* xb    = (short*)(ws + off_xb);
  short* wqkvb = (short*)(ws + off_wqkvb);
  short* wprjb = (short*)(ws + off_wprjb);
  short* qkvb  = (short*)(ws + off_qkvb);
  short* Qfp   = (short*)(ws + off_q);
  short* Kfp   = (short*)(ws + off_k);
  short* Vfp   = (short*)(ws + off_vt);
  short* AOp   = (short*)(ws + off_ao);
  float2* tab  = (float2*)(ws + off_tab);
  short* Opp   = (short*)(ws + off_op);
  float* lpp   = (float*)(ws + off_l);

  prep<<<dim3(5632), dim3(256), 0, stream>>>(x, Wqkv, Wproj, xb, wqkvb, wprjb, tab);

  gemm_bt<0><<<dim3(64, 12), dim3(256), 0, stream>>>(xb, wqkvb, bqkv, qkvb, M_, K3_, C_);

  rope_vt<<<dim3(3072), dim3(256), 0, stream>>>(qkvb, tab, Qfp, Kfp, Vfp);

  attn<<<dim3(16, 32, NCH), dim3(256), 0, stream>>>(Qfp, Kfp, Vfp, Opp, lpp);
  combine<<<dim3(2048), dim3(256), 0, stream>>>(Opp, lpp, AOp);

  gemm_bt<1><<<dim3(64, 4), dim3(256), 0, stream>>>(AOp, wprjb, bproj, (void*)out, M_, C_, C_);
}

// Round 12
// 141.043 us; speedup vs baseline: 5.0482x; 1.0182x over previous
//
#include <hip/hip_runtime.h>
#include <hip/hip_bf16.h>
#include <stdint.h>

#define B_ 2
#define N_ 4096
#define C_ 512
#define H_ 8
#define D_ 64
#define M_ (B_*N_)     // 8192
#define K3_ (3*C_)     // 1536
#define NCH 2          // KV-split ways

typedef __attribute__((ext_vector_type(8)))  short short8;
typedef __attribute__((ext_vector_type(4)))  float f32x4;
typedef __attribute__((ext_vector_type(16))) float f32x16;

// ---------- helpers ----------
static __device__ __forceinline__ unsigned short f2bf(float f) {
  union { float f; unsigned u; } cv; cv.f = f;
  unsigned r = cv.u + 0x7fffu + ((cv.u >> 16) & 1u);   // RNE
  return (unsigned short)(r >> 16);
}
static __device__ __forceinline__ float bf2f(short x) {
  union { unsigned u; float f; } cv;
  cv.u = ((unsigned)(unsigned short)x) << 16;
  return cv.f;
}
static __device__ __forceinline__ float fexp2(float x) {
#if __has_builtin(__builtin_amdgcn_exp2f)
  return __builtin_amdgcn_exp2f(x);
#else
  return exp2f(x);
#endif
}
static __device__ __forceinline__ unsigned cvt_pk_bf16(float a, float b) {
  unsigned r;
  asm("v_cvt_pk_bf16_f32 %0, %1, %2" : "=v"(r) : "v"(a), "v"(b));
  return r;   // lo = bf16(a), hi = bf16(b)
}
static __device__ __forceinline__ void gload_lds16(const void* g, void* l) {
  __builtin_amdgcn_global_load_lds((const __attribute__((address_space(1))) unsigned*)g,
                                   (__attribute__((address_space(3))) unsigned*)l, 16, 0, 0);
}
static __device__ __forceinline__ f32x16 zero16() {
  f32x16 z;
#pragma unroll
  for (int i = 0; i < 16; i++) z[i] = 0.f;
  return z;
}

// ---------- prep: casts + rope table in one launch ----------
__global__ void prep(const float* __restrict__ x, const float* __restrict__ Wqkv,
                     const float* __restrict__ Wproj,
                     short* __restrict__ xb, short* __restrict__ wqkvb,
                     short* __restrict__ wprjb, float2* __restrict__ tab) {
  int blk = blockIdx.x, t = threadIdx.x;
  if (blk < 4096) {
    int i = blk * 256 + t;
    float4 v = ((const float4*)x)[i];
    short4 o;
    o.x = (short)f2bf(v.x); o.y = (short)f2bf(v.y);
    o.z = (short)f2bf(v.z); o.w = (short)f2bf(v.w);
    ((short4*)xb)[i] = o;
  } else if (blk < 4864) {
    int i = (blk - 4096) * 256 + t;
    float4 v = ((const float4*)Wqkv)[i];
    short4 o;
    o.x = (short)f2bf(v.x); o.y = (short)f2bf(v.y);
    o.z = (short)f2bf(v.z); o.w = (short)f2bf(v.w);
    ((short4*)wqkvb)[i] = o;
  } else if (blk < 5120) {
    int i = (blk - 4864) * 256 + t;
    float4 v = ((const float4*)Wproj)[i];
    short4 o;
    o.x = (short)f2bf(v.x); o.y = (short)f2bf(v.y);
    o.z = (short)f2bf(v.z); o.w = (short)f2bf(v.w);
    ((short4*)wprjb)[i] = o;
  } else {
    int i = (blk - 5120) * 256 + t;   // 4096*32
    int p = i & 31, n = i >> 5;
    float freq = exp2f(-((float)(2 * p) / 64.0f) * 13.287712379549449f);
    float ang = (float)n * freq;
    float s, c;
    sincosf(ang, &s, &c);
    float2 r; r.x = c; r.y = s;
    tab[i] = r;
  }
}

// ---------- rope (coalesced LDS-staged) + V frag transpose, one launch ----------
__global__ void rope_vt(const short* __restrict__ qkvb, const float2* __restrict__ tab,
                        short* __restrict__ Qf, short* __restrict__ Kf,
                        short* __restrict__ Vf) {
  __shared__ short tile[128][72];
  int blk = blockIdx.x, t = threadIdx.x;
  if (blk < 1024) {
    int tk = blk >> 9;
    int bh = (blk & 511) >> 5;
    int nb4 = blk & 31;
    int b = bh >> 3, h = bh & 7;
    int n0 = nb4 * 128;
#pragma unroll
    for (int pass = 0; pass < 4; pass++) {
      int row = pass * 32 + (t >> 3), chunk = t & 7;
      short8 v = *(const short8*)(qkvb + (size_t)(b * N_ + n0 + row) * K3_ + tk * C_ + h * D_ + chunk * 8);
      *(short8*)&tile[row][chunk * 8] = v;
    }
    __syncthreads();
    int lane = t & 63, f = t >> 6;
    int c = lane & 31, hi = lane >> 5;
    int d0 = f * 16 + hi * 8;
    float sc = (tk == 0) ? 0.18033688011112042f : 1.0f;  // SCALE * log2(e) on Q
    short* base = (tk ? Kf : Qf);
#pragma unroll
    for (int i = 0; i < 4; i++) {
      int n_l = i * 32 + c;
      short8 v = *(const short8*)&tile[n_l][d0];
      const float2* tp = tab + (size_t)(n0 + n_l) * 32 + (d0 >> 1);
      short8 w;
#pragma unroll
      for (int j = 0; j < 4; j++) {
        float e = bf2f(v[2 * j]), o = bf2f(v[2 * j + 1]);
        float2 cs = tp[j];
        float e2 = (e * cs.x - o * cs.y) * sc;
        float o2 = (e * cs.y + o * cs.x) * sc;
        w[2 * j] = (short)f2bf(e2);
        w[2 * j + 1] = (short)f2bf(o2);
      }
      short* dst = base + (((size_t)(bh * 128 + nb4 * 4 + i) * 4 + f) * 512) + lane * 8;
      *(short8*)dst = w;
    }
  } else {
    int blk2 = blk - 1024;             // 2048
    int bh = blk2 >> 7, kblk = blk2 & 127;
    int b = bh >> 3, h = bh & 7;
    int n0 = kblk * 32;
    {
      int row = t >> 3, c8 = t & 7;
      short8 v = *(const short8*)(qkvb + (size_t)(b * N_ + n0 + row) * K3_ + 2 * C_ + h * D_ + c8 * 8);
      *(short8*)&tile[row][c8 * 8] = v;
    }
    __syncthreads();
    {
      int frag = t >> 6, lane = t & 63;
      int hi = lane >> 5, c = lane & 31;
      int g = frag & 1, dblk = frag >> 1;
      short8 w;
#pragma unroll
      for (int j = 0; j < 8; j++) w[j] = tile[g * 16 + hi * 8 + j][dblk * 32 + c];
      *(short8*)(Vf + ((size_t)(bh * 128 + kblk) * 4 + frag) * 512 + lane * 8) = w;
    }
  }
}

// ---------- GEMM: BK=64, XOR-swizzled LDS (pre-swizzled global source), MFR m-frags/wave ----------
template<int OUTF32, int MFR>
__global__ __launch_bounds__(256) void gemm_bt(const short* __restrict__ A, const short* __restrict__ Bw,
                                               const float* __restrict__ bias, void* __restrict__ Cout,
                                               int M, int Nout, int K) {
  __shared__ short As[MFR * 32 * 64];
  __shared__ short Bs[128 * 64];
  int t = threadIdx.x, lane = t & 63, w = t >> 6, wr = w >> 1, wc = w & 1;
  int tM = blockIdx.x * (MFR * 32), tN = blockIdx.y * 128;
  int lrow = lane & 15, lhi = lane >> 4;
  int rs = (lrow & 7) * 8;                    // reader XOR (elements)
  f32x4 acc[MFR][4];
#pragma unroll
  for (int fm = 0; fm < MFR; fm++)
#pragma unroll
    for (int fn = 0; fn < 4; fn++)
#pragma unroll
      for (int r = 0; r < 4; r++) acc[fm][fn][r] = 0.f;

  int srow = t >> 3;                          // 0..31 within a 32-row group
  int sq = ((t & 7) * 8) ^ ((srow & 7) * 8);  // pre-swizzled source k-offset (elements)

  for (int k0 = 0; k0 < K; k0 += 64) {
#pragma unroll
    for (int p = 0; p < MFR; p++)
      gload_lds16(A + (size_t)(tM + p * 32 + srow) * K + k0 + sq, As + p * 2048 + t * 8);
#pragma unroll
    for (int p = 0; p < 4; p++)
      gload_lds16(Bw + (size_t)(tN + p * 32 + srow) * K + k0 + sq, Bs + p * 2048 + t * 8);
    __syncthreads();
#pragma unroll
    for (int kk = 0; kk < 2; kk++) {
      int ko = (kk * 32 + lhi * 8) ^ rs;
      short8 af[MFR], bfr[4];
#pragma unroll
      for (int f = 0; f < MFR; f++)
        af[f] = *(const short8*)(As + (wr * (MFR * 16) + f * 16 + lrow) * 64 + ko);
#pragma unroll
      for (int f = 0; f < 4; f++)
        bfr[f] = *(const short8*)(Bs + (wc * 64 + f * 16 + lrow) * 64 + ko);
#pragma unroll
      for (int fm = 0; fm < MFR; fm++)
#pragma unroll
        for (int fn = 0; fn < 4; fn++)
          acc[fm][fn] = __builtin_amdgcn_mfma_f32_16x16x32_bf16(af[fm], bfr[fn], acc[fm][fn], 0, 0, 0);
    }
    __syncthreads();
  }

#pragma unroll
  for (int fn = 0; fn < 4; fn++) {
    int col = tN + wc * 64 + fn * 16 + lrow;
    float bv = bias[col];
#pragma unroll
    for (int fm = 0; fm < MFR; fm++) {
      int row0 = tM + wr * (MFR * 16) + fm * 16 + lhi * 4;
#pragma unroll
      for (int r = 0; r < 4; r++) {
        float v = acc[fm][fn][r] + bv;
        if (OUTF32) ((float*)Cout)[(size_t)(row0 + r) * Nout + col] = v;
        else        ((short*)Cout)[(size_t)(row0 + r) * Nout + col] = (short)f2bf(v);
      }
    }
  }
}

// ---------- attn building blocks ----------
static __device__ __forceinline__ f32x16 qk4(const short8* k, const short8* q, const f32x16& z0) {
  __builtin_amdgcn_s_setprio(1);
  f32x16 st = __builtin_amdgcn_mfma_f32_32x32x16_bf16(k[0], q[0], z0, 0, 0, 0);
  st = __builtin_amdgcn_mfma_f32_32x32x16_bf16(k[1], q[1], st, 0, 0, 0);
  st = __builtin_amdgcn_mfma_f32_32x32x16_bf16(k[2], q[2], st, 0, 0, 0);
  st = __builtin_amdgcn_mfma_f32_32x32x16_bf16(k[3], q[3], st, 0, 0, 0);
  __builtin_amdgcn_s_setprio(0);
  return st;
}
static __device__ __forceinline__ void soft_pv(const f32x16& st, const short8* v, const short8& ones,
                                               f32x16& o0, f32x16& o1, f32x16& o2) {
  unsigned cpk[8];
#pragma unroll
  for (int q2 = 0; q2 < 4; q2++) {
    float e0 = fexp2(st[4 * q2]),     e1 = fexp2(st[4 * q2 + 1]);
    float e2 = fexp2(st[4 * q2 + 2]), e3 = fexp2(st[4 * q2 + 3]);
    cpk[2 * q2]     = cvt_pk_bf16(e0, e1);
    cpk[2 * q2 + 1] = cvt_pk_bf16(e2, e3);
  }
  unsigned w00 = cpk[0], w02 = cpk[2];
  asm volatile("v_permlane32_swap_b32 %0, %1" : "+v"(w00), "+v"(w02));
  unsigned w01 = cpk[1], w03 = cpk[3];
  asm volatile("v_permlane32_swap_b32 %0, %1" : "+v"(w01), "+v"(w03));
  unsigned w10 = cpk[4], w12 = cpk[6];
  asm volatile("v_permlane32_swap_b32 %0, %1" : "+v"(w10), "+v"(w12));
  unsigned w11 = cpk[5], w13 = cpk[7];
  asm volatile("v_permlane32_swap_b32 %0, %1" : "+v"(w11), "+v"(w13));
  union { unsigned u[4]; short8 s; } u0, u1;
  u0.u[0] = w00; u0.u[1] = w01; u0.u[2] = w02; u0.u[3] = w03;
  u1.u[0] = w10; u1.u[1] = w11; u1.u[2] = w12; u1.u[3] = w13;
  __builtin_amdgcn_s_setprio(1);
  o0 = __builtin_amdgcn_mfma_f32_32x32x16_bf16(u0.s, v[0], o0, 0, 0, 0);
  o0 = __builtin_amdgcn_mfma_f32_32x32x16_bf16(u1.s, v[1], o0, 0, 0, 0);
  o1 = __builtin_amdgcn_mfma_f32_32x32x16_bf16(u0.s, v[2], o1, 0, 0, 0);
  o1 = __builtin_amdgcn_mfma_f32_32x32x16_bf16(u1.s, v[3], o1, 0, 0, 0);
  o2 = __builtin_amdgcn_mfma_f32_32x32x16_bf16(u0.s, ones, o2, 0, 0, 0);
  o2 = __builtin_amdgcn_mfma_f32_32x32x16_bf16(u1.s, ones, o2, 0, 0, 0);
  __builtin_amdgcn_s_setprio(0);
}

// ---------- Flash attention: 2-way KV split, 64-kv double-buffered LDS, MFMA row-sums ----------
__global__ __launch_bounds__(256, 4) void attn(const short* __restrict__ Qf, const short* __restrict__ Kf,
                                               const short* __restrict__ Vf,
                                               short* __restrict__ Op, float* __restrict__ lp) {
  __shared__ short Ks[2][4096];
  __shared__ short Vs[2][4096];
  int bh = blockIdx.x;
  int ch = blockIdx.z;
  int t = threadIdx.x;
  int wv = t >> 6, lane = t & 63;
  int c = lane & 31, hi = lane >> 5;
  int q0 = blockIdx.y * 128 + wv * 32;
  const int nkb2 = N_ / (NCH * 64);          // 32 iters of 64 kv
  int kb0 = ch * (N_ / (NCH * 32));          // in 32-kv block units

  const short* Qb = Qf + ((size_t)(bh * 128 + (q0 >> 5)) * 4) * 512 + lane * 8;
  const short* Kg = Kf + ((size_t)(bh * 128 + kb0) * 4) * 512 + t * 8;
  const short* Vg = Vf + ((size_t)(bh * 128 + kb0) * 4) * 512 + t * 8;

  short8 qf4[4];
#pragma unroll
  for (int f = 0; f < 4; f++) qf4[f] = *(const short8*)(Qb + f * 512);

  short8 ones;
#pragma unroll
  for (int j = 0; j < 8; j++) ones[j] = (short)0x3F80;   // bf16 1.0

  const f32x16 z0 = zero16();
  f32x16 o0 = z0, o1 = z0, o2 = z0;

  gload_lds16(Kg,        &Ks[0][t * 8]);
  gload_lds16(Kg + 2048, &Ks[0][2048 + t * 8]);
  gload_lds16(Vg,        &Vs[0][t * 8]);
  gload_lds16(Vg + 2048, &Vs[0][2048 + t * 8]);
  __syncthreads();

  int buf = 0;
  for (int it = 0; it < nkb2; ++it) {
    if (it + 1 < nkb2) {
      const short* Kn = Kg + (size_t)(it + 1) * 4096;
      const short* Vn = Vg + (size_t)(it + 1) * 4096;
      gload_lds16(Kn,        &Ks[buf ^ 1][t * 8]);
      gload_lds16(Kn + 2048, &Ks[buf ^ 1][2048 + t * 8]);
      gload_lds16(Vn,        &Vs[buf ^ 1][t * 8]);
      gload_lds16(Vn + 2048, &Vs[buf ^ 1][2048 + t * 8]);
    }
#pragma unroll
    for (int s = 0; s < 2; s++) {
      short8 kf[4], vf[4];
#pragma unroll
      for (int f = 0; f < 4; f++) kf[f] = *(const short8*)&Ks[buf][s * 2048 + f * 512 + lane * 8];
#pragma unroll
      for (int f = 0; f < 4; f++) vf[f] = *(const short8*)&Vs[buf][s * 2048 + f * 512 + lane * 8];
      f32x16 st = qk4(kf, qf4, z0);
      soft_pv(st, vf, ones, o0, o1, o2);
    }
    __syncthreads();
    buf ^= 1;
  }

  if (c == 0) {
    float* lrow = lp + ((size_t)ch * 16 + bh) * N_ + q0;
#pragma unroll
    for (int r = 0; r < 16; r++) lrow[(r & 3) + 8 * (r >> 2) + 4 * hi] = o2[r];
  }
  short* obase = Op + ((size_t)ch * 16 + bh) * N_ * D_;
#pragma unroll
  for (int r = 0; r < 16; r++) {
    int ql = (r & 3) + 8 * (r >> 2) + 4 * hi;
    int n = q0 + ql;
    obase[(size_t)n * D_ + c]      = (short)f2bf(o0[r]);
    obase[(size_t)n * D_ + 32 + c] = (short)f2bf(o1[r]);
  }
}

// ---------- combine bf16 partials -> AO bf16 ----------
__global__ void combine(const short* __restrict__ Op, const float* __restrict__ lp,
                        short* __restrict__ AO) {
  int i = blockIdx.x * blockDim.x + threadIdx.x;   // 16*4096*8
  if (i >= 16 * N_ * 8) return;
  int d8 = i & 7, q = (i >> 3) & (N_ - 1), bh = i >> 15;
  const size_t chs = (size_t)16 * N_ * D_;
  size_t base = ((size_t)bh * N_ + q) * D_ + d8 * 8;
  float acc[8];
#pragma unroll
  for (int j = 0; j < 8; j++) acc[j] = 0.f;
  float l = 0.f;
#pragma unroll
  for (int chv = 0; chv < NCH; chv++) {
    short8 v = *(const short8*)(Op + chv * chs + base);
#pragma unroll
    for (int j = 0; j < 8; j++) acc[j] += bf2f(v[j]);
    l += lp[((size_t)chv * 16 + bh) * N_ + q];
  }
  float inv = 1.0f / l;
  int bb = bh >> 3, h = bh & 7;
  short8 o;
#pragma unroll
  for (int j = 0; j < 8; j++) o[j] = (short)f2bf(acc[j] * inv);
  *(short8*)(AO + ((size_t)(bb * N_ + q)) * C_ + h * D_ + d8 * 8) = o;
}

// ---------- launch ----------
extern "C" void kernel_launch(void* const* d_in, const int* in_sizes, int n_in,
                              void* d_out, int out_size, void* d_ws, size_t ws_size,
                              hipStream_t stream) {
  const float* x     = (const float*)d_in[0];
  const float* Wqkv  = (const float*)d_in[1];
  const float* bqkv  = (const float*)d_in[2];
  const float* Wproj = (const float*)d_in[3];
  const float* bproj = (const float*)d_in[4];
  float* out = (float*)d_out;
  char* ws = (char*)d_ws;

  // persistent region
  const size_t off_wprjb = 0;          // 524,288
  const size_t off_tab   = 524288;     // 1,048,576
  const size_t off_q     = 1572864;    // 8,388,608
  const size_t off_k     = 9961472;    // 8,388,608
  const size_t off_vt    = 18350080;   // 8,388,608
  const size_t off_ao    = 26738688;   // 8,388,608 -> ends 35,127,296
  // phase-1 transient (aliased below by partials)
  const size_t off_xb    = 35127296;   // 8,388,608
  const size_t off_wqkvb = 43515904;   // 1,572,864
  const size_t off_qkvb  = 45088768;   // 25,165,824 -> ends 70,254,592
  // attn-phase partials (alias xb/wqkvb/qkvb)
  const size_t off_op    = 35127296;   // 2*16*4096*64*2 = 16,777,216
  const size_t off_l     = 68681728;   // 2*16*4096*4    =    524,288
  if (ws_size < 70254592) return;

  short* xb    = (short*)(ws + off_xb);
  short* wqkvb = (short*)(ws + off_wqkvb);
  short* wprjb = (short*)(ws + off_wprjb);
  short* qkvb  = (short*)(ws + off_qkvb);
  short* Qfp   = (short*)(ws + off_q);
  short* Kfp   = (short*)(ws + off_k);
  short* Vfp   = (short*)(ws + off_vt);
  short* AOp   = (short*)(ws + off_ao);
  float2* tab  = (float2*)(ws + off_tab);
  short* Opp   = (short*)(ws + off_op);
  float* lpp   = (float*)(ws + off_l);

  prep<<<dim3(5632), dim3(256), 0, stream>>>(x, Wqkv, Wproj, xb, wqkvb, wprjb, tab);

  gemm_bt<0, 4><<<dim3(64, 12), dim3(256), 0, stream>>>(xb, wqkvb, bqkv, qkvb, M_, K3_, C_);

  rope_vt<<<dim3(3072), dim3(256), 0, stream>>>(qkvb, tab, Qfp, Kfp, Vfp);

  attn<<<dim3(16, 32, NCH), dim3(256), 0, stream>>>(Qfp, Kfp, Vfp, Opp, lpp);
  combine<<<dim3(2048), dim3(256), 0, stream>>>(Opp, lpp, AOp);

  gemm_bt<1, 2><<<dim3(128, 4), dim3(256), 0, stream>>>(AOp, wprjb, bproj, (void*)out, M_, C_, C_);
}

// Round 13
// 134.508 us; speedup vs baseline: 5.2935x; 1.0486x over previous
//
#include <hip/hip_runtime.h>
#include <hip/hip_bf16.h>
#include <stdint.h>

#define B_ 2
#define N_ 4096
#define C_ 512
#define H_ 8
#define D_ 64
#define M_ (B_*N_)     // 8192
#define K3_ (3*C_)     // 1536
#define NCH 2          // KV-split ways

typedef __attribute__((ext_vector_type(8)))  short short8;
typedef __attribute__((ext_vector_type(4)))  float f32x4;
typedef __attribute__((ext_vector_type(16))) float f32x16;

// ---------- helpers ----------
static __device__ __forceinline__ unsigned short f2bf(float f) {
  union { float f; unsigned u; } cv; cv.f = f;
  unsigned r = cv.u + 0x7fffu + ((cv.u >> 16) & 1u);   // RNE
  return (unsigned short)(r >> 16);
}
static __device__ __forceinline__ float bf2f(short x) {
  union { unsigned u; float f; } cv;
  cv.u = ((unsigned)(unsigned short)x) << 16;
  return cv.f;
}
static __device__ __forceinline__ float fexp2(float x) {
#if __has_builtin(__builtin_amdgcn_exp2f)
  return __builtin_amdgcn_exp2f(x);
#else
  return exp2f(x);
#endif
}
static __device__ __forceinline__ unsigned cvt_pk_bf16(float a, float b) {
  unsigned r;
  asm("v_cvt_pk_bf16_f32 %0, %1, %2" : "=v"(r) : "v"(a), "v"(b));
  return r;   // lo = bf16(a), hi = bf16(b)
}
static __device__ __forceinline__ void gload_lds16(const void* g, void* l) {
  __builtin_amdgcn_global_load_lds((const __attribute__((address_space(1))) unsigned*)g,
                                   (__attribute__((address_space(3))) unsigned*)l, 16, 0, 0);
}
static __device__ __forceinline__ f32x16 zero16() {
  f32x16 z;
#pragma unroll
  for (int i = 0; i < 16; i++) z[i] = 0.f;
  return z;
}

// ---------- prep: casts + rope table in one launch ----------
__global__ void prep(const float* __restrict__ x, const float* __restrict__ Wqkv,
                     const float* __restrict__ Wproj,
                     short* __restrict__ xb, short* __restrict__ wqkvb,
                     short* __restrict__ wprjb, float2* __restrict__ tab) {
  int blk = blockIdx.x, t = threadIdx.x;
  if (blk < 4096) {
    int i = blk * 256 + t;
    float4 v = ((const float4*)x)[i];
    short4 o;
    o.x = (short)f2bf(v.x); o.y = (short)f2bf(v.y);
    o.z = (short)f2bf(v.z); o.w = (short)f2bf(v.w);
    ((short4*)xb)[i] = o;
  } else if (blk < 4864) {
    int i = (blk - 4096) * 256 + t;
    float4 v = ((const float4*)Wqkv)[i];
    short4 o;
    o.x = (short)f2bf(v.x); o.y = (short)f2bf(v.y);
    o.z = (short)f2bf(v.z); o.w = (short)f2bf(v.w);
    ((short4*)wqkvb)[i] = o;
  } else if (blk < 5120) {
    int i = (blk - 4864) * 256 + t;
    float4 v = ((const float4*)Wproj)[i];
    short4 o;
    o.x = (short)f2bf(v.x); o.y = (short)f2bf(v.y);
    o.z = (short)f2bf(v.z); o.w = (short)f2bf(v.w);
    ((short4*)wprjb)[i] = o;
  } else {
    int i = (blk - 5120) * 256 + t;   // 4096*32
    int p = i & 31, n = i >> 5;
    float freq = exp2f(-((float)(2 * p) / 64.0f) * 13.287712379549449f);
    float ang = (float)n * freq;
    float s, c;
    sincosf(ang, &s, &c);
    float2 r; r.x = c; r.y = s;
    tab[i] = r;
  }
}

// ---------- rope (coalesced LDS-staged) + V frag transpose, one launch ----------
__global__ void rope_vt(const short* __restrict__ qkvb, const float2* __restrict__ tab,
                        short* __restrict__ Qf, short* __restrict__ Kf,
                        short* __restrict__ Vf) {
  __shared__ short tile[128][72];
  int blk = blockIdx.x, t = threadIdx.x;
  if (blk < 1024) {
    int tk = blk >> 9;
    int bh = (blk & 511) >> 5;
    int nb4 = blk & 31;
    int b = bh >> 3, h = bh & 7;
    int n0 = nb4 * 128;
#pragma unroll
    for (int pass = 0; pass < 4; pass++) {
      int row = pass * 32 + (t >> 3), chunk = t & 7;
      short8 v = *(const short8*)(qkvb + (size_t)(b * N_ + n0 + row) * K3_ + tk * C_ + h * D_ + chunk * 8);
      *(short8*)&tile[row][chunk * 8] = v;
    }
    __syncthreads();
    int lane = t & 63, f = t >> 6;
    int c = lane & 31, hi = lane >> 5;
    int d0 = f * 16 + hi * 8;
    float sc = (tk == 0) ? 0.18033688011112042f : 1.0f;  // SCALE * log2(e) on Q
    short* base = (tk ? Kf : Qf);
#pragma unroll
    for (int i = 0; i < 4; i++) {
      int n_l = i * 32 + c;
      short8 v = *(const short8*)&tile[n_l][d0];
      const float2* tp = tab + (size_t)(n0 + n_l) * 32 + (d0 >> 1);
      short8 w;
#pragma unroll
      for (int j = 0; j < 4; j++) {
        float e = bf2f(v[2 * j]), o = bf2f(v[2 * j + 1]);
        float2 cs = tp[j];
        float e2 = (e * cs.x - o * cs.y) * sc;
        float o2 = (e * cs.y + o * cs.x) * sc;
        w[2 * j] = (short)f2bf(e2);
        w[2 * j + 1] = (short)f2bf(o2);
      }
      short* dst = base + (((size_t)(bh * 128 + nb4 * 4 + i) * 4 + f) * 512) + lane * 8;
      *(short8*)dst = w;
    }
  } else {
    int blk2 = blk - 1024;             // 2048
    int bh = blk2 >> 7, kblk = blk2 & 127;
    int b = bh >> 3, h = bh & 7;
    int n0 = kblk * 32;
    {
      int row = t >> 3, c8 = t & 7;
      short8 v = *(const short8*)(qkvb + (size_t)(b * N_ + n0 + row) * K3_ + 2 * C_ + h * D_ + c8 * 8);
      *(short8*)&tile[row][c8 * 8] = v;
    }
    __syncthreads();
    {
      int frag = t >> 6, lane = t & 63;
      int hi = lane >> 5, c = lane & 31;
      int g = frag & 1, dblk = frag >> 1;
      short8 w;
#pragma unroll
      for (int j = 0; j < 8; j++) w[j] = tile[g * 16 + hi * 8 + j][dblk * 32 + c];
      *(short8*)(Vf + ((size_t)(bh * 128 + kblk) * 4 + frag) * 512 + lane * 8) = w;
    }
  }
}

// ---------- GEMM: BK=64, XOR-swizzled LDS (pre-swizzled global source), MFR m-frags/wave ----------
template<int OUTF32, int MFR>
__global__ __launch_bounds__(256) void gemm_bt(const short* __restrict__ A, const short* __restrict__ Bw,
                                               const float* __restrict__ bias, void* __restrict__ Cout,
                                               int M, int Nout, int K) {
  __shared__ short As[MFR * 32 * 64];
  __shared__ short Bs[128 * 64];
  int t = threadIdx.x, lane = t & 63, w = t >> 6, wr = w >> 1, wc = w & 1;
  int tM = blockIdx.x * (MFR * 32), tN = blockIdx.y * 128;
  int lrow = lane & 15, lhi = lane >> 4;
  int rs = (lrow & 7) * 8;                    // reader XOR (elements)
  f32x4 acc[MFR][4];
#pragma unroll
  for (int fm = 0; fm < MFR; fm++)
#pragma unroll
    for (int fn = 0; fn < 4; fn++)
#pragma unroll
      for (int r = 0; r < 4; r++) acc[fm][fn][r] = 0.f;

  int srow = t >> 3;                          // 0..31 within a 32-row group
  int sq = ((t & 7) * 8) ^ ((srow & 7) * 8);  // pre-swizzled source k-offset (elements)

  for (int k0 = 0; k0 < K; k0 += 64) {
#pragma unroll
    for (int p = 0; p < MFR; p++)
      gload_lds16(A + (size_t)(tM + p * 32 + srow) * K + k0 + sq, As + p * 2048 + t * 8);
#pragma unroll
    for (int p = 0; p < 4; p++)
      gload_lds16(Bw + (size_t)(tN + p * 32 + srow) * K + k0 + sq, Bs + p * 2048 + t * 8);
    __syncthreads();
#pragma unroll
    for (int kk = 0; kk < 2; kk++) {
      int ko = (kk * 32 + lhi * 8) ^ rs;
      short8 af[MFR], bfr[4];
#pragma unroll
      for (int f = 0; f < MFR; f++)
        af[f] = *(const short8*)(As + (wr * (MFR * 16) + f * 16 + lrow) * 64 + ko);
#pragma unroll
      for (int f = 0; f < 4; f++)
        bfr[f] = *(const short8*)(Bs + (wc * 64 + f * 16 + lrow) * 64 + ko);
#pragma unroll
      for (int fm = 0; fm < MFR; fm++)
#pragma unroll
        for (int fn = 0; fn < 4; fn++)
          acc[fm][fn] = __builtin_amdgcn_mfma_f32_16x16x32_bf16(af[fm], bfr[fn], acc[fm][fn], 0, 0, 0);
    }
    __syncthreads();
  }

#pragma unroll
  for (int fn = 0; fn < 4; fn++) {
    int col = tN + wc * 64 + fn * 16 + lrow;
    float bv = bias[col];
#pragma unroll
    for (int fm = 0; fm < MFR; fm++) {
      int row0 = tM + wr * (MFR * 16) + fm * 16 + lhi * 4;
#pragma unroll
      for (int r = 0; r < 4; r++) {
        float v = acc[fm][fn][r] + bv;
        if (OUTF32) ((float*)Cout)[(size_t)(row0 + r) * Nout + col] = v;
        else        ((short*)Cout)[(size_t)(row0 + r) * Nout + col] = (short)f2bf(v);
      }
    }
  }
}

// ---------- attn building blocks ----------
static __device__ __forceinline__ f32x16 qk4(const short8* k, const short8* q, const f32x16& z0) {
  __builtin_amdgcn_s_setprio(1);
  f32x16 st = __builtin_amdgcn_mfma_f32_32x32x16_bf16(k[0], q[0], z0, 0, 0, 0);
  st = __builtin_amdgcn_mfma_f32_32x32x16_bf16(k[1], q[1], st, 0, 0, 0);
  st = __builtin_amdgcn_mfma_f32_32x32x16_bf16(k[2], q[2], st, 0, 0, 0);
  st = __builtin_amdgcn_mfma_f32_32x32x16_bf16(k[3], q[3], st, 0, 0, 0);
  __builtin_amdgcn_s_setprio(0);
  return st;
}
static __device__ __forceinline__ void soft_pv(const f32x16& st, const short8* v, const short8& ones,
                                               f32x16& o0, f32x16& o1, f32x16& o2) {
  unsigned cpk[8];
#pragma unroll
  for (int q2 = 0; q2 < 4; q2++) {
    float e0 = fexp2(st[4 * q2]),     e1 = fexp2(st[4 * q2 + 1]);
    float e2 = fexp2(st[4 * q2 + 2]), e3 = fexp2(st[4 * q2 + 3]);
    cpk[2 * q2]     = cvt_pk_bf16(e0, e1);
    cpk[2 * q2 + 1] = cvt_pk_bf16(e2, e3);
  }
  unsigned w00 = cpk[0], w02 = cpk[2];
  asm volatile("v_permlane32_swap_b32 %0, %1" : "+v"(w00), "+v"(w02));
  unsigned w01 = cpk[1], w03 = cpk[3];
  asm volatile("v_permlane32_swap_b32 %0, %1" : "+v"(w01), "+v"(w03));
  unsigned w10 = cpk[4], w12 = cpk[6];
  asm volatile("v_permlane32_swap_b32 %0, %1" : "+v"(w10), "+v"(w12));
  unsigned w11 = cpk[5], w13 = cpk[7];
  asm volatile("v_permlane32_swap_b32 %0, %1" : "+v"(w11), "+v"(w13));
  union { unsigned u[4]; short8 s; } u0, u1;
  u0.u[0] = w00; u0.u[1] = w01; u0.u[2] = w02; u0.u[3] = w03;
  u1.u[0] = w10; u1.u[1] = w11; u1.u[2] = w12; u1.u[3] = w13;
  __builtin_amdgcn_s_setprio(1);
  o0 = __builtin_amdgcn_mfma_f32_32x32x16_bf16(u0.s, v[0], o0, 0, 0, 0);
  o0 = __builtin_amdgcn_mfma_f32_32x32x16_bf16(u1.s, v[1], o0, 0, 0, 0);
  o1 = __builtin_amdgcn_mfma_f32_32x32x16_bf16(u0.s, v[2], o1, 0, 0, 0);
  o1 = __builtin_amdgcn_mfma_f32_32x32x16_bf16(u1.s, v[3], o1, 0, 0, 0);
  o2 = __builtin_amdgcn_mfma_f32_32x32x16_bf16(u0.s, ones, o2, 0, 0, 0);
  o2 = __builtin_amdgcn_mfma_f32_32x32x16_bf16(u1.s, ones, o2, 0, 0, 0);
  __builtin_amdgcn_s_setprio(0);
}

// ---------- Flash attention: 64 q-rows/wave (2 halves share K/V frag reads), 2-way KV split ----------
__global__ __launch_bounds__(256, 2) void attn(const short* __restrict__ Qf, const short* __restrict__ Kf,
                                               const short* __restrict__ Vf,
                                               short* __restrict__ Op, float* __restrict__ lp) {
  __shared__ short Ks[2][4096];
  __shared__ short Vs[2][4096];
  int bh = blockIdx.x;
  int ch = blockIdx.z;
  int t = threadIdx.x;
  int wv = t >> 6, lane = t & 63;
  int c = lane & 31, hi = lane >> 5;
  int q0 = blockIdx.y * 256 + wv * 64;       // this wave: q0..q0+63
  const int nkb2 = N_ / (NCH * 64);          // 32 iters of 64 kv
  int kb0 = ch * (N_ / (NCH * 32));          // in 32-kv block units

  const short* QbA = Qf + ((size_t)(bh * 128 + (q0 >> 5)) * 4) * 512 + lane * 8;
  const short* Kg = Kf + ((size_t)(bh * 128 + kb0) * 4) * 512 + t * 8;
  const short* Vg = Vf + ((size_t)(bh * 128 + kb0) * 4) * 512 + t * 8;

  short8 qA[4], qB[4];
#pragma unroll
  for (int f = 0; f < 4; f++) qA[f] = *(const short8*)(QbA + f * 512);
#pragma unroll
  for (int f = 0; f < 4; f++) qB[f] = *(const short8*)(QbA + (4 + f) * 512);

  short8 ones;
#pragma unroll
  for (int j = 0; j < 8; j++) ones[j] = (short)0x3F80;   // bf16 1.0

  const f32x16 z0 = zero16();
  f32x16 oA0 = z0, oA1 = z0, oA2 = z0;
  f32x16 oB0 = z0, oB1 = z0, oB2 = z0;

  gload_lds16(Kg,        &Ks[0][t * 8]);
  gload_lds16(Kg + 2048, &Ks[0][2048 + t * 8]);
  gload_lds16(Vg,        &Vs[0][t * 8]);
  gload_lds16(Vg + 2048, &Vs[0][2048 + t * 8]);
  __syncthreads();

  int buf = 0;
  for (int it = 0; it < nkb2; ++it) {
    if (it + 1 < nkb2) {
      const short* Kn = Kg + (size_t)(it + 1) * 4096;
      const short* Vn = Vg + (size_t)(it + 1) * 4096;
      gload_lds16(Kn,        &Ks[buf ^ 1][t * 8]);
      gload_lds16(Kn + 2048, &Ks[buf ^ 1][2048 + t * 8]);
      gload_lds16(Vn,        &Vs[buf ^ 1][t * 8]);
      gload_lds16(Vn + 2048, &Vs[buf ^ 1][2048 + t * 8]);
    }
#pragma unroll
    for (int s = 0; s < 2; s++) {
      short8 kf[4], vf[4];
#pragma unroll
      for (int f = 0; f < 4; f++) kf[f] = *(const short8*)&Ks[buf][s * 2048 + f * 512 + lane * 8];
#pragma unroll
      for (int f = 0; f < 4; f++) vf[f] = *(const short8*)&Vs[buf][s * 2048 + f * 512 + lane * 8];
      f32x16 stA = qk4(kf, qA, z0);
      f32x16 stB = qk4(kf, qB, z0);
      soft_pv(stA, vf, ones, oA0, oA1, oA2);
      soft_pv(stB, vf, ones, oB0, oB1, oB2);
    }
    __syncthreads();
    buf ^= 1;
  }

  float* lrow = lp + ((size_t)ch * 16 + bh) * N_ + q0;
  short* obase = Op + ((size_t)ch * 16 + bh) * N_ * D_;
  if (c == 0) {
#pragma unroll
    for (int r = 0; r < 16; r++) {
      int ql = (r & 3) + 8 * (r >> 2) + 4 * hi;
      lrow[ql] = oA2[r];
      lrow[32 + ql] = oB2[r];
    }
  }
#pragma unroll
  for (int r = 0; r < 16; r++) {
    int ql = (r & 3) + 8 * (r >> 2) + 4 * hi;
    size_t nA = (size_t)(q0 + ql) * D_;
    size_t nB = (size_t)(q0 + 32 + ql) * D_;
    obase[nA + c]      = (short)f2bf(oA0[r]);
    obase[nA + 32 + c] = (short)f2bf(oA1[r]);
    obase[nB + c]      = (short)f2bf(oB0[r]);
    obase[nB + 32 + c] = (short)f2bf(oB1[r]);
  }
}

// ---------- combine bf16 partials -> AO bf16 ----------
__global__ void combine(const short* __restrict__ Op, const float* __restrict__ lp,
                        short* __restrict__ AO) {
  int i = blockIdx.x * blockDim.x + threadIdx.x;   // 16*4096*8
  if (i >= 16 * N_ * 8) return;
  int d8 = i & 7, q = (i >> 3) & (N_ - 1), bh = i >> 15;
  const size_t chs = (size_t)16 * N_ * D_;
  size_t base = ((size_t)bh * N_ + q) * D_ + d8 * 8;
  float acc[8];
#pragma unroll
  for (int j = 0; j < 8; j++) acc[j] = 0.f;
  float l = 0.f;
#pragma unroll
  for (int chv = 0; chv < NCH; chv++) {
    short8 v = *(const short8*)(Op + chv * chs + base);
#pragma unroll
    for (int j = 0; j < 8; j++) acc[j] += bf2f(v[j]);
    l += lp[((size_t)chv * 16 + bh) * N_ + q];
  }
  float inv = 1.0f / l;
  int bb = bh >> 3, h = bh & 7;
  short8 o;
#pragma unroll
  for (int j = 0; j < 8; j++) o[j] = (short)f2bf(acc[j] * inv);
  *(short8*)(AO + ((size_t)(bb * N_ + q)) * C_ + h * D_ + d8 * 8) = o;
}

// ---------- launch ----------
extern "C" void kernel_launch(void* const* d_in, const int* in_sizes, int n_in,
                              void* d_out, int out_size, void* d_ws, size_t ws_size,
                              hipStream_t stream) {
  const float* x     = (const float*)d_in[0];
  const float* Wqkv  = (const float*)d_in[1];
  const float* bqkv  = (const float*)d_in[2];
  const float* Wproj = (const float*)d_in[3];
  const float* bproj = (const float*)d_in[4];
  float* out = (float*)d_out;
  char* ws = (char*)d_ws;

  // persistent region
  const size_t off_wprjb = 0;          // 524,288
  const size_t off_tab   = 524288;     // 1,048,576
  const size_t off_q     = 1572864;    // 8,388,608
  const size_t off_k     = 9961472;    // 8,388,608
  const size_t off_vt    = 18350080;   // 8,388,608
  const size_t off_ao    = 26738688;   // 8,388,608 -> ends 35,127,296
  // phase-1 transient (aliased below by partials)
  const size_t off_xb    = 35127296;   // 8,388,608
  const size_t off_wqkvb = 43515904;   // 1,572,864
  const size_t off_qkvb  = 45088768;   // 25,165,824 -> ends 70,254,592
  // attn-phase partials (alias xb/wqkvb/qkvb)
  const size_t off_op    = 35127296;   // 2*16*4096*64*2 = 16,777,216
  const size_t off_l     = 68681728;   // 2*16*4096*4    =    524,288
  if (ws_size < 70254592) return;

  short* xb    = (short*)(ws + off_xb);
  short* wqkvb = (short*)(ws + off_wqkvb);
  short* wprjb = (short*)(ws + off_wprjb);
  short* qkvb  = (short*)(ws + off_qkvb);
  short* Qfp   = (short*)(ws + off_q);
  short* Kfp   = (short*)(ws + off_k);
  short* Vfp   = (short*)(ws + off_vt);
  short* AOp   = (short*)(ws + off_ao);
  float2* tab  = (float2*)(ws + off_tab);
  short* Opp   = (short*)(ws + off_op);
  float* lpp   = (float*)(ws + off_l);

  prep<<<dim3(5632), dim3(256), 0, stream>>>(x, Wqkv, Wproj, xb, wqkvb, wprjb, tab);

  gemm_bt<0, 4><<<dim3(64, 12), dim3(256), 0, stream>>>(xb, wqkvb, bqkv, qkvb, M_, K3_, C_);

  rope_vt<<<dim3(3072), dim3(256), 0, stream>>>(qkvb, tab, Qfp, Kfp, Vfp);

  attn<<<dim3(16, 16, NCH), dim3(256), 0, stream>>>(Qfp, Kfp, Vfp, Opp, lpp);
  combine<<<dim3(2048), dim3(256), 0, stream>>>(Opp, lpp, AOp);

  gemm_bt<1, 2><<<dim3(128, 4), dim3(256), 0, stream>>>(AOp, wprjb, bproj, (void*)out, M_, C_, C_);
}